// Round 1
// baseline (850.311 us; speedup 1.0000x reference)
//
#include <hip/hip_runtime.h>

constexpr int IND = 128;
constexpr int HID = 64;
constexpr float BN_EPS = 1e-5f;

__global__ __launch_bounds__(256) void k_deg_init(float* __restrict__ deg, int N) {
  int i = blockIdx.x * 256 + threadIdx.x;
  if (i < N) deg[i] = 1.0f;
}

__global__ __launch_bounds__(256) void k_deg_count(const int* __restrict__ col,
                                                   float* __restrict__ deg, int E) {
  int e = blockIdx.x * 256 + threadIdx.x;
  if (e < E) unsafeAtomicAdd(&deg[col[e]], 1.0f);
}

__global__ __launch_bounds__(256) void k_rsqrt(float* __restrict__ deg, int N) {
  int i = blockIdx.x * 256 + threadIdx.x;
  if (i < N) deg[i] = rsqrtf(deg[i]);
}

// h = x @ W^T ; x:[N,128], W:[64,128] row-major, h:[N,64]
__global__ __launch_bounds__(256) void k_matmul(const float* __restrict__ x,
                                                const float* __restrict__ W,
                                                float* __restrict__ h, int N) {
  __shared__ float ws[IND * HID];  // [k][c] transposed
  __shared__ float xs[64 * IND];   // [n][k]
  const int tid = threadIdx.x;
  const int nb = blockIdx.x * 64;

  // stage W transposed: ws[k*64+c] = W[c*128+k]
  for (int id = tid; id < 2048; id += 256) {
    int c = id & 63;
    int k4 = (id >> 6) << 2;
    float4 w = *(const float4*)&W[c * IND + k4];
    ws[(k4 + 0) * HID + c] = w.x;
    ws[(k4 + 1) * HID + c] = w.y;
    ws[(k4 + 2) * HID + c] = w.z;
    ws[(k4 + 3) * HID + c] = w.w;
  }
  // stage 64 x-rows (coalesced)
  for (int id = tid; id < 2048; id += 256) {
    int n = id >> 5;
    int k4 = (id & 31) << 2;
    float4 v = make_float4(0.f, 0.f, 0.f, 0.f);
    if (nb + n < N) v = *(const float4*)&x[(size_t)(nb + n) * IND + k4];
    *(float4*)&xs[n * IND + k4] = v;
  }
  __syncthreads();

  const int c0 = (tid & 15) << 2;   // 4 channels per thread
  const int n0 = (tid >> 4) << 2;   // 4 nodes per thread
  float acc[4][4] = {};
  for (int k = 0; k < IND; k += 4) {
    float4 w0 = *(const float4*)&ws[(k + 0) * HID + c0];
    float4 w1 = *(const float4*)&ws[(k + 1) * HID + c0];
    float4 w2 = *(const float4*)&ws[(k + 2) * HID + c0];
    float4 w3 = *(const float4*)&ws[(k + 3) * HID + c0];
#pragma unroll
    for (int j = 0; j < 4; ++j) {
      float4 xv = *(const float4*)&xs[(n0 + j) * IND + k];
      acc[j][0] += xv.x * w0.x + xv.y * w1.x + xv.z * w2.x + xv.w * w3.x;
      acc[j][1] += xv.x * w0.y + xv.y * w1.y + xv.z * w2.y + xv.w * w3.y;
      acc[j][2] += xv.x * w0.z + xv.y * w1.z + xv.z * w2.z + xv.w * w3.z;
      acc[j][3] += xv.x * w0.w + xv.y * w1.w + xv.z * w2.w + xv.w * w3.w;
    }
  }
#pragma unroll
  for (int j = 0; j < 4; ++j) {
    int node = nb + n0 + j;
    if (node < N)
      *(float4*)&h[(size_t)node * HID + c0] =
          make_float4(acc[j][0], acc[j][1], acc[j][2], acc[j][3]);
  }
}

// scatter: acc[col] += dis[row]*dis[col]*h[row]  (+ self loops e>=E)
__global__ __launch_bounds__(256) void k_scatter(const int* __restrict__ row,
                                                 const int* __restrict__ col,
                                                 const float* __restrict__ dis,
                                                 const float* __restrict__ h,
                                                 float* __restrict__ acc,
                                                 int E, int N) {
  int gid = blockIdx.x * 256 + threadIdx.x;
  int e = gid >> 4;
  if (e >= E + N) return;
  int cq = (gid & 15) << 2;
  int r, c;
  if (e < E) { r = row[e]; c = col[e]; }
  else       { r = e - E;  c = r; }
  float norm = dis[r] * dis[c];
  float4 hv = *(const float4*)&h[(size_t)r * HID + cq];
  float* dst = &acc[(size_t)c * HID + cq];
  unsafeAtomicAdd(dst + 0, norm * hv.x);
  unsafeAtomicAdd(dst + 1, norm * hv.y);
  unsafeAtomicAdd(dst + 2, norm * hv.z);
  unsafeAtomicAdd(dst + 3, norm * hv.w);
}

// per-channel sum & sumsq of relu(acc+bias); per-block partials (no atomics)
__global__ __launch_bounds__(256) void k_stats(const float* __restrict__ acc,
                                               const float* __restrict__ bias,
                                               float* __restrict__ partials,
                                               int total4) {
  __shared__ float ls[4][64];
  __shared__ float lq[4][64];
  int tid = threadIdx.x;
  int start = blockIdx.x * 256 + tid;
  int stride = gridDim.x * 256;
  int c0 = (tid & 15) << 2;  // constant per thread (stride % 16 == 0)
  float4 bv = *(const float4*)&bias[c0];
  float s0 = 0, s1 = 0, s2 = 0, s3 = 0, q0 = 0, q1 = 0, q2 = 0, q3 = 0;
  for (int i = start; i < total4; i += stride) {
    float4 v = *(const float4*)&acc[(size_t)i * 4];
    float y0 = fmaxf(v.x + bv.x, 0.f);
    float y1 = fmaxf(v.y + bv.y, 0.f);
    float y2 = fmaxf(v.z + bv.z, 0.f);
    float y3 = fmaxf(v.w + bv.w, 0.f);
    s0 += y0; s1 += y1; s2 += y2; s3 += y3;
    q0 += y0 * y0; q1 += y1 * y1; q2 += y2 * y2; q3 += y3 * y3;
  }
  // reduce across lanes sharing the same channel quad (l, l^16, l^32, l^48)
  s0 += __shfl_xor(s0, 16); s0 += __shfl_xor(s0, 32);
  s1 += __shfl_xor(s1, 16); s1 += __shfl_xor(s1, 32);
  s2 += __shfl_xor(s2, 16); s2 += __shfl_xor(s2, 32);
  s3 += __shfl_xor(s3, 16); s3 += __shfl_xor(s3, 32);
  q0 += __shfl_xor(q0, 16); q0 += __shfl_xor(q0, 32);
  q1 += __shfl_xor(q1, 16); q1 += __shfl_xor(q1, 32);
  q2 += __shfl_xor(q2, 16); q2 += __shfl_xor(q2, 32);
  q3 += __shfl_xor(q3, 16); q3 += __shfl_xor(q3, 32);
  int wave = tid >> 6, lane = tid & 63;
  if (lane < 16) {
    ls[wave][c0 + 0] = s0; ls[wave][c0 + 1] = s1;
    ls[wave][c0 + 2] = s2; ls[wave][c0 + 3] = s3;
    lq[wave][c0 + 0] = q0; lq[wave][c0 + 1] = q1;
    lq[wave][c0 + 2] = q2; lq[wave][c0 + 3] = q3;
  }
  __syncthreads();
  if (tid < 64) {
    float s = ls[0][tid] + ls[1][tid] + ls[2][tid] + ls[3][tid];
    float q = lq[0][tid] + lq[1][tid] + lq[2][tid] + lq[3][tid];
    partials[blockIdx.x * 128 + tid] = s;
    partials[blockIdx.x * 128 + 64 + tid] = q;
  }
}

__global__ __launch_bounds__(256) void k_reduce(const float* __restrict__ partials,
                                                float* __restrict__ st, int nb) {
  __shared__ float tmp[256];
  int tid = threadIdx.x;
  int c = tid & 127;
  int half = tid >> 7;
  int hb = nb >> 1;
  float s = 0.f;
  for (int b = half * hb; b < (half + 1) * hb; ++b) s += partials[b * 128 + c];
  tmp[tid] = s;
  __syncthreads();
  if (tid < 128) st[tid] = tmp[tid] + tmp[tid + 128];
}

__global__ __launch_bounds__(256) void k_finalize(float* __restrict__ out,
                                                  const float* __restrict__ st,
                                                  const float* __restrict__ bias,
                                                  const float* __restrict__ gamma,
                                                  const float* __restrict__ beta,
                                                  float invN, int total4) {
  int tid = threadIdx.x;
  int start = blockIdx.x * 256 + tid;
  int stride = gridDim.x * 256;
  int c0 = (tid & 15) << 2;
  float sc[4], sh[4], bz[4];
#pragma unroll
  for (int j = 0; j < 4; ++j) {
    int c = c0 + j;
    float mean = st[c] * invN;
    float var = st[64 + c] * invN - mean * mean;
    float istd = rsqrtf(var + BN_EPS);
    float g = gamma[c] * istd;
    sc[j] = g;
    sh[j] = beta[c] - mean * g;
    bz[j] = bias[c];
  }
  for (int i = start; i < total4; i += stride) {
    float4 v = *(float4*)&out[(size_t)i * 4];
    float y0 = fmaxf(v.x + bz[0], 0.f);
    float y1 = fmaxf(v.y + bz[1], 0.f);
    float y2 = fmaxf(v.z + bz[2], 0.f);
    float y3 = fmaxf(v.w + bz[3], 0.f);
    float4 o = make_float4(y0 * sc[0] + sh[0], y1 * sc[1] + sh[1],
                           y2 * sc[2] + sh[2], y3 * sc[3] + sh[3]);
    *(float4*)&out[(size_t)i * 4] = o;
  }
}

extern "C" void kernel_launch(void* const* d_in, const int* in_sizes, int n_in,
                              void* d_out, int out_size, void* d_ws, size_t ws_size,
                              hipStream_t stream) {
  const float* x = (const float*)d_in[0];
  const int* ei = (const int*)d_in[1];
  const float* W = (const float*)d_in[3];
  const float* bias = (const float*)d_in[4];
  const float* gamma = (const float*)d_in[5];
  const float* beta = (const float*)d_in[6];
  const int N = in_sizes[0] / IND;
  const int E = in_sizes[1] / 2;
  const int* rowp = ei;        // sources
  const int* colp = ei + E;    // targets
  float* out = (float*)d_out;

  char* wsb = (char*)d_ws;
  float* dis = (float*)wsb;                       // N floats (deg -> rsqrt in place)
  size_t off = ((size_t)N * 4 + 255) & ~(size_t)255;
  float* h = (float*)(wsb + off);                 // N*64 floats
  off += (size_t)N * HID * 4;
  off = (off + 255) & ~(size_t)255;
  float* partials = (float*)(wsb + off);          // 256*128 floats
  off += 256 * 128 * 4;
  float* st = (float*)(wsb + off);                // 128 floats

  // accumulator = d_out; must be zeroed every launch (harness poisons once)
  hipMemsetAsync(d_out, 0, (size_t)out_size * sizeof(float), stream);

  k_deg_init<<<(N + 255) / 256, 256, 0, stream>>>(dis, N);
  k_deg_count<<<(E + 255) / 256, 256, 0, stream>>>(colp, dis, E);
  k_rsqrt<<<(N + 255) / 256, 256, 0, stream>>>(dis, N);
  k_matmul<<<(N + 63) / 64, 256, 0, stream>>>(x, W, h, N);

  long long tw = (long long)(E + N) * 16;
  k_scatter<<<(int)((tw + 255) / 256), 256, 0, stream>>>(rowp, colp, dis, h, out, E, N);

  int total4 = N * (HID / 4);
  k_stats<<<256, 256, 0, stream>>>(out, bias, partials, total4);
  k_reduce<<<1, 256, 0, stream>>>(partials, st, 256);
  k_finalize<<<256, 256, 0, stream>>>(out, st, bias, gamma, beta, 1.0f / (float)N, total4);
}

// Round 2
// 217.051 us; speedup vs baseline: 3.9176x; 3.9176x over previous
//
#include <hip/hip_runtime.h>

constexpr int IND = 128;
constexpr int HID = 64;
constexpr float BN_EPS = 1e-5f;

static inline size_t align256(size_t x) { return (x + 255) & ~(size_t)255; }

// ---------- degree / dis ----------
__global__ __launch_bounds__(256) void k_deg_count(const int* __restrict__ col,
                                                   int* __restrict__ cnt, int E) {
  int e = blockIdx.x * 256 + threadIdx.x;
  if (e < E) atomicAdd(&cnt[col[e]], 1);
}

__global__ __launch_bounds__(256) void k_dis(const int* __restrict__ cnt,
                                             float* __restrict__ dis, int N) {
  int i = blockIdx.x * 256 + threadIdx.x;
  if (i < N) dis[i] = rsqrtf((float)(cnt[i] + 1));  // +1 self-loop
}

// ---------- hierarchical exclusive scan of cnt[N] ----------
__global__ __launch_bounds__(256) void k_scan1(const int* __restrict__ cnt,
                                               int* __restrict__ bsum, int N) {
  __shared__ int ls[4];
  int i = blockIdx.x * 256 + threadIdx.x;
  int v = (i < N) ? cnt[i] : 0;
#pragma unroll
  for (int s = 1; s < 64; s <<= 1) v += __shfl_xor(v, s);
  int wave = threadIdx.x >> 6;
  if ((threadIdx.x & 63) == 0) ls[wave] = v;
  __syncthreads();
  if (threadIdx.x == 0) bsum[blockIdx.x] = ls[0] + ls[1] + ls[2] + ls[3];
}

__global__ __launch_bounds__(256) void k_scan2(const int* __restrict__ bsum,
                                               int* __restrict__ bexc, int NB) {
  __shared__ int a[256];
  int tid = threadIdx.x;
  int v = (tid < NB) ? bsum[tid] : 0;
  a[tid] = v;
  __syncthreads();
#pragma unroll
  for (int s = 1; s < 256; s <<= 1) {
    int t = (tid >= s) ? a[tid - s] : 0;
    __syncthreads();
    a[tid] += t;
    __syncthreads();
  }
  bexc[tid] = a[tid] - v;  // exclusive
}

__global__ __launch_bounds__(256) void k_scan3(const int* __restrict__ cnt,
                                               const int* __restrict__ bexc,
                                               int* __restrict__ offsets,
                                               int* __restrict__ cursor, int N) {
  __shared__ int a[256];
  int tid = threadIdx.x;
  int i = blockIdx.x * 256 + tid;
  int v = (i < N) ? cnt[i] : 0;
  a[tid] = v;
  __syncthreads();
#pragma unroll
  for (int s = 1; s < 256; s <<= 1) {
    int t = (tid >= s) ? a[tid - s] : 0;
    __syncthreads();
    a[tid] += t;
    __syncthreads();
  }
  if (i < N) {
    int exc = a[tid] - v + bexc[blockIdx.x];
    offsets[i] = exc;
    cursor[i] = exc;
  }
}

// ---------- placement: pack[pos] = {src, norm} grouped by target ----------
__global__ __launch_bounds__(256) void k_place(const int* __restrict__ row,
                                               const int* __restrict__ col,
                                               const float* __restrict__ dis,
                                               int* __restrict__ cursor,
                                               int2* __restrict__ pack, int E) {
  int e = blockIdx.x * 256 + threadIdx.x;
  if (e >= E) return;
  int r = row[e], c = col[e];
  float nrm = dis[r] * dis[c];
  int pos = atomicAdd(&cursor[c], 1);
  pack[pos] = make_int2(r, __float_as_int(nrm));
}

// ---------- h = x @ W^T ----------
__global__ __launch_bounds__(256) void k_matmul(const float* __restrict__ x,
                                                const float* __restrict__ W,
                                                float* __restrict__ h, int N) {
  __shared__ float ws[IND * HID];  // [k][c]
  __shared__ float xs[64 * IND];   // [n][k]
  const int tid = threadIdx.x;
  const int nb = blockIdx.x * 64;

  for (int id = tid; id < 2048; id += 256) {
    int c = id & 63;
    int k4 = (id >> 6) << 2;
    float4 w = *(const float4*)&W[c * IND + k4];
    ws[(k4 + 0) * HID + c] = w.x;
    ws[(k4 + 1) * HID + c] = w.y;
    ws[(k4 + 2) * HID + c] = w.z;
    ws[(k4 + 3) * HID + c] = w.w;
  }
  for (int id = tid; id < 2048; id += 256) {
    int n = id >> 5;
    int k4 = (id & 31) << 2;
    float4 v = make_float4(0.f, 0.f, 0.f, 0.f);
    if (nb + n < N) v = *(const float4*)&x[(size_t)(nb + n) * IND + k4];
    *(float4*)&xs[n * IND + k4] = v;
  }
  __syncthreads();

  const int c0 = (tid & 15) << 2;
  const int n0 = (tid >> 4) << 2;
  float acc[4][4] = {};
  for (int k = 0; k < IND; k += 4) {
    float4 w0 = *(const float4*)&ws[(k + 0) * HID + c0];
    float4 w1 = *(const float4*)&ws[(k + 1) * HID + c0];
    float4 w2 = *(const float4*)&ws[(k + 2) * HID + c0];
    float4 w3 = *(const float4*)&ws[(k + 3) * HID + c0];
#pragma unroll
    for (int j = 0; j < 4; ++j) {
      float4 xv = *(const float4*)&xs[(n0 + j) * IND + k];
      acc[j][0] += xv.x * w0.x + xv.y * w1.x + xv.z * w2.x + xv.w * w3.x;
      acc[j][1] += xv.x * w0.y + xv.y * w1.y + xv.z * w2.y + xv.w * w3.y;
      acc[j][2] += xv.x * w0.z + xv.y * w1.z + xv.z * w2.z + xv.w * w3.z;
      acc[j][3] += xv.x * w0.w + xv.y * w1.w + xv.z * w2.w + xv.w * w3.w;
    }
  }
#pragma unroll
  for (int j = 0; j < 4; ++j) {
    int node = nb + n0 + j;
    if (node < N)
      *(float4*)&h[(size_t)node * HID + c0] =
          make_float4(acc[j][0], acc[j][1], acc[j][2], acc[j][3]);
  }
}

// ---------- gather: one wave per node, lane = channel ----------
__global__ __launch_bounds__(256) void k_gather(const int* __restrict__ offsets,
                                                const int* __restrict__ ends,
                                                const int2* __restrict__ pack,
                                                const float* __restrict__ dis,
                                                const float* __restrict__ h,
                                                float* __restrict__ out, int N) {
  int wid = (blockIdx.x * 256 + threadIdx.x) >> 6;
  int lane = threadIdx.x & 63;
  if (wid >= N) return;
  int off = offsets[wid];
  int end = ends[wid];  // cursor after placement == offsets[i+1]
  float d = dis[wid];
  float acc = d * d * h[(size_t)wid * HID + lane];  // self-loop
  int j = off;
  // 2-deep manual pipeline: pack load for j+1 overlaps h load for j
  int2 p = (j < end) ? pack[j] : make_int2(0, 0);
  for (; j < end;) {
    int2 cur = p;
    ++j;
    if (j < end) p = pack[j];
    acc += __int_as_float(cur.y) * h[(size_t)cur.x * HID + lane];
  }
  out[(size_t)wid * HID + lane] = acc;
}

// ---------- BN stats ----------
__global__ __launch_bounds__(256) void k_stats(const float* __restrict__ acc,
                                               const float* __restrict__ bias,
                                               float* __restrict__ partials,
                                               int total4) {
  __shared__ float ls[4][64];
  __shared__ float lq[4][64];
  int tid = threadIdx.x;
  int start = blockIdx.x * 256 + tid;
  int stride = gridDim.x * 256;
  int c0 = (tid & 15) << 2;
  float4 bv = *(const float4*)&bias[c0];
  float s0 = 0, s1 = 0, s2 = 0, s3 = 0, q0 = 0, q1 = 0, q2 = 0, q3 = 0;
  for (int i = start; i < total4; i += stride) {
    float4 v = *(const float4*)&acc[(size_t)i * 4];
    float y0 = fmaxf(v.x + bv.x, 0.f);
    float y1 = fmaxf(v.y + bv.y, 0.f);
    float y2 = fmaxf(v.z + bv.z, 0.f);
    float y3 = fmaxf(v.w + bv.w, 0.f);
    s0 += y0; s1 += y1; s2 += y2; s3 += y3;
    q0 += y0 * y0; q1 += y1 * y1; q2 += y2 * y2; q3 += y3 * y3;
  }
  s0 += __shfl_xor(s0, 16); s0 += __shfl_xor(s0, 32);
  s1 += __shfl_xor(s1, 16); s1 += __shfl_xor(s1, 32);
  s2 += __shfl_xor(s2, 16); s2 += __shfl_xor(s2, 32);
  s3 += __shfl_xor(s3, 16); s3 += __shfl_xor(s3, 32);
  q0 += __shfl_xor(q0, 16); q0 += __shfl_xor(q0, 32);
  q1 += __shfl_xor(q1, 16); q1 += __shfl_xor(q1, 32);
  q2 += __shfl_xor(q2, 16); q2 += __shfl_xor(q2, 32);
  q3 += __shfl_xor(q3, 16); q3 += __shfl_xor(q3, 32);
  int wave = tid >> 6, lane = tid & 63;
  if (lane < 16) {
    ls[wave][c0 + 0] = s0; ls[wave][c0 + 1] = s1;
    ls[wave][c0 + 2] = s2; ls[wave][c0 + 3] = s3;
    lq[wave][c0 + 0] = q0; lq[wave][c0 + 1] = q1;
    lq[wave][c0 + 2] = q2; lq[wave][c0 + 3] = q3;
  }
  __syncthreads();
  if (tid < 64) {
    float s = ls[0][tid] + ls[1][tid] + ls[2][tid] + ls[3][tid];
    float q = lq[0][tid] + lq[1][tid] + lq[2][tid] + lq[3][tid];
    partials[blockIdx.x * 128 + tid] = s;
    partials[blockIdx.x * 128 + 64 + tid] = q;
  }
}

__global__ __launch_bounds__(256) void k_reduce(const float* __restrict__ partials,
                                                float* __restrict__ st, int nb) {
  __shared__ float tmp[256];
  int tid = threadIdx.x;
  int c = tid & 127;
  int half = tid >> 7;
  int hb = nb >> 1;
  float s = 0.f;
  for (int b = half * hb; b < (half + 1) * hb; ++b) s += partials[b * 128 + c];
  tmp[tid] = s;
  __syncthreads();
  if (tid < 128) st[tid] = tmp[tid] + tmp[tid + 128];
}

__global__ __launch_bounds__(256) void k_finalize(float* __restrict__ out,
                                                  const float* __restrict__ st,
                                                  const float* __restrict__ bias,
                                                  const float* __restrict__ gamma,
                                                  const float* __restrict__ beta,
                                                  float invN, int total4) {
  int tid = threadIdx.x;
  int start = blockIdx.x * 256 + tid;
  int stride = gridDim.x * 256;
  int c0 = (tid & 15) << 2;
  float sc[4], sh[4], bz[4];
#pragma unroll
  for (int j = 0; j < 4; ++j) {
    int c = c0 + j;
    float mean = st[c] * invN;
    float var = st[64 + c] * invN - mean * mean;
    float istd = rsqrtf(var + BN_EPS);
    float g = gamma[c] * istd;
    sc[j] = g;
    sh[j] = beta[c] - mean * g;
    bz[j] = bias[c];
  }
  for (int i = start; i < total4; i += stride) {
    float4 v = *(float4*)&out[(size_t)i * 4];
    float y0 = fmaxf(v.x + bz[0], 0.f);
    float y1 = fmaxf(v.y + bz[1], 0.f);
    float y2 = fmaxf(v.z + bz[2], 0.f);
    float y3 = fmaxf(v.w + bz[3], 0.f);
    float4 o = make_float4(y0 * sc[0] + sh[0], y1 * sc[1] + sh[1],
                           y2 * sc[2] + sh[2], y3 * sc[3] + sh[3]);
    *(float4*)&out[(size_t)i * 4] = o;
  }
}

extern "C" void kernel_launch(void* const* d_in, const int* in_sizes, int n_in,
                              void* d_out, int out_size, void* d_ws, size_t ws_size,
                              hipStream_t stream) {
  const float* x = (const float*)d_in[0];
  const int* ei = (const int*)d_in[1];
  const float* W = (const float*)d_in[3];
  const float* bias = (const float*)d_in[4];
  const float* gamma = (const float*)d_in[5];
  const float* beta = (const float*)d_in[6];
  const int N = in_sizes[0] / IND;
  const int E = in_sizes[1] / 2;
  const int* rowp = ei;      // sources
  const int* colp = ei + E;  // targets
  float* out = (float*)d_out;

  // workspace carve-up (~20 MB)
  char* wsb = (char*)d_ws;
  size_t off = 0;
  float* dis = (float*)(wsb + off);   off = align256(off + (size_t)N * 4);
  int* cnt = (int*)(wsb + off);       off = align256(off + (size_t)N * 4);
  int* offsets = (int*)(wsb + off);   off = align256(off + (size_t)N * 4);
  int* cursor = (int*)(wsb + off);    off = align256(off + (size_t)N * 4);
  int* bsum = (int*)(wsb + off);      off = align256(off + 1024);
  int* bexc = (int*)(wsb + off);      off = align256(off + 1024);
  float* partials = (float*)(wsb + off); off = align256(off + 256 * 128 * 4);
  float* st = (float*)(wsb + off);    off = align256(off + 512);
  float* h = (float*)(wsb + off);     off = align256(off + (size_t)N * HID * 4);
  int2* pack = (int2*)(wsb + off);    off = align256(off + (size_t)E * 8);

  const int NB = (N + 255) / 256;  // 196 <= 256

  hipMemsetAsync(cnt, 0, (size_t)N * 4, stream);
  k_deg_count<<<(E + 255) / 256, 256, 0, stream>>>(colp, cnt, E);
  k_dis<<<NB, 256, 0, stream>>>(cnt, dis, N);
  k_scan1<<<NB, 256, 0, stream>>>(cnt, bsum, N);
  k_scan2<<<1, 256, 0, stream>>>(bsum, bexc, NB);
  k_scan3<<<NB, 256, 0, stream>>>(cnt, bexc, offsets, cursor, N);
  k_place<<<(E + 255) / 256, 256, 0, stream>>>(rowp, colp, dis, cursor, pack, E);
  k_matmul<<<(N + 63) / 64, 256, 0, stream>>>(x, W, h, N);
  k_gather<<<(N * 64 + 255) / 256, 256, 0, stream>>>(offsets, cursor, pack, dis, h,
                                                     out, N);
  int total4 = N * (HID / 4);
  k_stats<<<256, 256, 0, stream>>>(out, bias, partials, total4);
  k_reduce<<<1, 256, 0, stream>>>(partials, st, 256);
  k_finalize<<<256, 256, 0, stream>>>(out, st, bias, gamma, beta, 1.0f / (float)N,
                                      total4);
}

// Round 3
// 193.307 us; speedup vs baseline: 4.3988x; 1.1228x over previous
//
#include <hip/hip_runtime.h>

constexpr int IND = 128;
constexpr int HID = 64;
constexpr float BN_EPS = 1e-5f;

static inline size_t align256(size_t x) { return (x + 255) & ~(size_t)255; }

__device__ inline ushort f2bf(float f) {
  uint u = __float_as_uint(f);
  uint r = (u + 0x7FFFu + ((u >> 16) & 1u)) >> 16;
  return (ushort)r;
}
__device__ inline float bf2f(ushort u) {
  return __uint_as_float(((uint)u) << 16);
}

// ---------- degree ----------
__global__ __launch_bounds__(256) void k_deg_count(const int* __restrict__ col,
                                                   int* __restrict__ cnt, int E) {
  int e = blockIdx.x * 256 + threadIdx.x;
  if (e < E) atomicAdd(&cnt[col[e]], 1);
}

// ---------- scan phase 1 (+ dis fused) ----------
__global__ __launch_bounds__(256) void k_scan1(const int* __restrict__ cnt,
                                               int* __restrict__ bsum,
                                               float* __restrict__ dis, int N) {
  __shared__ int ls[4];
  int i = blockIdx.x * 256 + threadIdx.x;
  int c = (i < N) ? cnt[i] : 0;
  if (i < N) dis[i] = rsqrtf((float)(c + 1));  // +1 self-loop
  int v = c;
#pragma unroll
  for (int s = 1; s < 64; s <<= 1) v += __shfl_xor(v, s);
  int wave = threadIdx.x >> 6;
  if ((threadIdx.x & 63) == 0) ls[wave] = v;
  __syncthreads();
  if (threadIdx.x == 0) bsum[blockIdx.x] = ls[0] + ls[1] + ls[2] + ls[3];
}

__global__ __launch_bounds__(256) void k_scan2(const int* __restrict__ bsum,
                                               int* __restrict__ bexc, int NB) {
  __shared__ int a[256];
  int tid = threadIdx.x;
  int v = (tid < NB) ? bsum[tid] : 0;
  a[tid] = v;
  __syncthreads();
#pragma unroll
  for (int s = 1; s < 256; s <<= 1) {
    int t = (tid >= s) ? a[tid - s] : 0;
    __syncthreads();
    a[tid] += t;
    __syncthreads();
  }
  bexc[tid] = a[tid] - v;  // exclusive
}

__global__ __launch_bounds__(256) void k_scan3(const int* __restrict__ cnt,
                                               const int* __restrict__ bexc,
                                               int* __restrict__ offsets,
                                               int* __restrict__ cursor, int N) {
  __shared__ int a[256];
  int tid = threadIdx.x;
  int i = blockIdx.x * 256 + tid;
  int v = (i < N) ? cnt[i] : 0;
  a[tid] = v;
  __syncthreads();
#pragma unroll
  for (int s = 1; s < 256; s <<= 1) {
    int t = (tid >= s) ? a[tid - s] : 0;
    __syncthreads();
    a[tid] += t;
    __syncthreads();
  }
  if (i < N) {
    int exc = a[tid] - v + bexc[blockIdx.x];
    offsets[i] = exc;
    cursor[i] = exc;
  }
}

// ---------- placement: pack[pos] = {src, norm} grouped by target ----------
__global__ __launch_bounds__(256) void k_place(const int* __restrict__ row,
                                               const int* __restrict__ col,
                                               const float* __restrict__ dis,
                                               int* __restrict__ cursor,
                                               int2* __restrict__ pack, int E) {
  int e = blockIdx.x * 256 + threadIdx.x;
  if (e >= E) return;
  int r = row[e], c = col[e];
  float nrm = dis[r] * dis[c];
  int pos = atomicAdd(&cursor[c], 1);
  pack[pos] = make_int2(r, __float_as_int(nrm));
}

// ---------- h = x @ W^T, stored bf16 ----------
__global__ __launch_bounds__(256) void k_matmul(const float* __restrict__ x,
                                                const float* __restrict__ W,
                                                ushort* __restrict__ h, int N) {
  __shared__ float ws[IND * HID];  // [k][c]
  __shared__ float xs[64 * IND];   // [n][k]
  const int tid = threadIdx.x;
  const int nb = blockIdx.x * 64;

  for (int id = tid; id < 2048; id += 256) {
    int c = id & 63;
    int k4 = (id >> 6) << 2;
    float4 w = *(const float4*)&W[c * IND + k4];
    ws[(k4 + 0) * HID + c] = w.x;
    ws[(k4 + 1) * HID + c] = w.y;
    ws[(k4 + 2) * HID + c] = w.z;
    ws[(k4 + 3) * HID + c] = w.w;
  }
  for (int id = tid; id < 2048; id += 256) {
    int n = id >> 5;
    int k4 = (id & 31) << 2;
    float4 v = make_float4(0.f, 0.f, 0.f, 0.f);
    if (nb + n < N) v = *(const float4*)&x[(size_t)(nb + n) * IND + k4];
    *(float4*)&xs[n * IND + k4] = v;
  }
  __syncthreads();

  const int c0 = (tid & 15) << 2;
  const int n0 = (tid >> 4) << 2;
  float acc[4][4] = {};
  for (int k = 0; k < IND; k += 4) {
    float4 w0 = *(const float4*)&ws[(k + 0) * HID + c0];
    float4 w1 = *(const float4*)&ws[(k + 1) * HID + c0];
    float4 w2 = *(const float4*)&ws[(k + 2) * HID + c0];
    float4 w3 = *(const float4*)&ws[(k + 3) * HID + c0];
#pragma unroll
    for (int j = 0; j < 4; ++j) {
      float4 xv = *(const float4*)&xs[(n0 + j) * IND + k];
      acc[j][0] += xv.x * w0.x + xv.y * w1.x + xv.z * w2.x + xv.w * w3.x;
      acc[j][1] += xv.x * w0.y + xv.y * w1.y + xv.z * w2.y + xv.w * w3.y;
      acc[j][2] += xv.x * w0.z + xv.y * w1.z + xv.z * w2.z + xv.w * w3.z;
      acc[j][3] += xv.x * w0.w + xv.y * w1.w + xv.z * w2.w + xv.w * w3.w;
    }
  }
#pragma unroll
  for (int j = 0; j < 4; ++j) {
    int node = nb + n0 + j;
    if (node < N) {
      ushort4 o;
      o.x = f2bf(acc[j][0]);
      o.y = f2bf(acc[j][1]);
      o.z = f2bf(acc[j][2]);
      o.w = f2bf(acc[j][3]);
      *(ushort4*)&h[(size_t)node * HID + c0] = o;
    }
  }
}

// ---------- gather: one wave per node, lane = channel, 4-edge ILP ----------
__global__ __launch_bounds__(256) void k_gather(const int* __restrict__ offsets,
                                                const int* __restrict__ ends,
                                                const int2* __restrict__ pack,
                                                const float* __restrict__ dis,
                                                const ushort* __restrict__ h,
                                                const float* __restrict__ bias,
                                                float* __restrict__ out, int N) {
  int wid = blockIdx.x * 4 + (threadIdx.x >> 6);
  int lane = threadIdx.x & 63;
  if (wid >= N) return;
  int off = __builtin_amdgcn_readfirstlane(offsets[wid]);
  int end = __builtin_amdgcn_readfirstlane(ends[wid]);
  float d = dis[wid];
  float a0 = d * d * bf2f(h[(size_t)wid * HID + lane]);  // self-loop
  float a1 = 0.f, a2 = 0.f, a3 = 0.f;
  int j = off;
  for (; j + 4 <= end; j += 4) {
    int2 p0 = pack[j + 0];
    int2 p1 = pack[j + 1];
    int2 p2 = pack[j + 2];
    int2 p3 = pack[j + 3];
    float h0 = bf2f(h[(size_t)p0.x * HID + lane]);
    float h1 = bf2f(h[(size_t)p1.x * HID + lane]);
    float h2 = bf2f(h[(size_t)p2.x * HID + lane]);
    float h3 = bf2f(h[(size_t)p3.x * HID + lane]);
    a0 += __int_as_float(p0.y) * h0;
    a1 += __int_as_float(p1.y) * h1;
    a2 += __int_as_float(p2.y) * h2;
    a3 += __int_as_float(p3.y) * h3;
  }
  for (; j < end; ++j) {
    int2 p = pack[j];
    a0 += __int_as_float(p.y) * bf2f(h[(size_t)p.x * HID + lane]);
  }
  float acc = (a0 + a1) + (a2 + a3);
  out[(size_t)wid * HID + lane] = fmaxf(acc + bias[lane], 0.f);
}

// ---------- BN stats over y = out (bias+relu already applied) ----------
__global__ __launch_bounds__(256) void k_stats(const float* __restrict__ y,
                                               float* __restrict__ partials,
                                               int total4) {
  __shared__ float ls[4][64];
  __shared__ float lq[4][64];
  int tid = threadIdx.x;
  int start = blockIdx.x * 256 + tid;
  int stride = gridDim.x * 256;
  int c0 = (tid & 15) << 2;
  float s0 = 0, s1 = 0, s2 = 0, s3 = 0, q0 = 0, q1 = 0, q2 = 0, q3 = 0;
  for (int i = start; i < total4; i += stride) {
    float4 v = *(const float4*)&y[(size_t)i * 4];
    s0 += v.x; s1 += v.y; s2 += v.z; s3 += v.w;
    q0 += v.x * v.x; q1 += v.y * v.y; q2 += v.z * v.z; q3 += v.w * v.w;
  }
  s0 += __shfl_xor(s0, 16); s0 += __shfl_xor(s0, 32);
  s1 += __shfl_xor(s1, 16); s1 += __shfl_xor(s1, 32);
  s2 += __shfl_xor(s2, 16); s2 += __shfl_xor(s2, 32);
  s3 += __shfl_xor(s3, 16); s3 += __shfl_xor(s3, 32);
  q0 += __shfl_xor(q0, 16); q0 += __shfl_xor(q0, 32);
  q1 += __shfl_xor(q1, 16); q1 += __shfl_xor(q1, 32);
  q2 += __shfl_xor(q2, 16); q2 += __shfl_xor(q2, 32);
  q3 += __shfl_xor(q3, 16); q3 += __shfl_xor(q3, 32);
  int wave = tid >> 6, lane = tid & 63;
  if (lane < 16) {
    ls[wave][c0 + 0] = s0; ls[wave][c0 + 1] = s1;
    ls[wave][c0 + 2] = s2; ls[wave][c0 + 3] = s3;
    lq[wave][c0 + 0] = q0; lq[wave][c0 + 1] = q1;
    lq[wave][c0 + 2] = q2; lq[wave][c0 + 3] = q3;
  }
  __syncthreads();
  if (tid < 64) {
    float s = ls[0][tid] + ls[1][tid] + ls[2][tid] + ls[3][tid];
    float q = lq[0][tid] + lq[1][tid] + lq[2][tid] + lq[3][tid];
    partials[blockIdx.x * 128 + tid] = s;
    partials[blockIdx.x * 128 + 64 + tid] = q;
  }
}

__global__ __launch_bounds__(256) void k_reduce(const float* __restrict__ partials,
                                                float* __restrict__ st, int nb) {
  __shared__ float tmp[256];
  int tid = threadIdx.x;
  int c = tid & 127;
  int half = tid >> 7;
  int hb = nb >> 1;
  float s = 0.f;
  for (int b = half * hb; b < (half + 1) * hb; ++b) s += partials[b * 128 + c];
  tmp[tid] = s;
  __syncthreads();
  if (tid < 128) st[tid] = tmp[tid] + tmp[tid + 128];
}

// ---------- BN normalize in place ----------
__global__ __launch_bounds__(256) void k_finalize(float* __restrict__ out,
                                                  const float* __restrict__ st,
                                                  const float* __restrict__ gamma,
                                                  const float* __restrict__ beta,
                                                  float invN, int total4) {
  int tid = threadIdx.x;
  int start = blockIdx.x * 256 + tid;
  int stride = gridDim.x * 256;
  int c0 = (tid & 15) << 2;
  float sc[4], sh[4];
#pragma unroll
  for (int j = 0; j < 4; ++j) {
    int c = c0 + j;
    float mean = st[c] * invN;
    float var = st[64 + c] * invN - mean * mean;
    float istd = rsqrtf(var + BN_EPS);
    float g = gamma[c] * istd;
    sc[j] = g;
    sh[j] = beta[c] - mean * g;
  }
  for (int i = start; i < total4; i += stride) {
    float4 v = *(float4*)&out[(size_t)i * 4];
    float4 o = make_float4(v.x * sc[0] + sh[0], v.y * sc[1] + sh[1],
                           v.z * sc[2] + sh[2], v.w * sc[3] + sh[3]);
    *(float4*)&out[(size_t)i * 4] = o;
  }
}

extern "C" void kernel_launch(void* const* d_in, const int* in_sizes, int n_in,
                              void* d_out, int out_size, void* d_ws, size_t ws_size,
                              hipStream_t stream) {
  const float* x = (const float*)d_in[0];
  const int* ei = (const int*)d_in[1];
  const float* W = (const float*)d_in[3];
  const float* bias = (const float*)d_in[4];
  const float* gamma = (const float*)d_in[5];
  const float* beta = (const float*)d_in[6];
  const int N = in_sizes[0] / IND;
  const int E = in_sizes[1] / 2;
  const int* rowp = ei;      // sources
  const int* colp = ei + E;  // targets
  float* out = (float*)d_out;

  char* wsb = (char*)d_ws;
  size_t off = 0;
  float* dis = (float*)(wsb + off);      off = align256(off + (size_t)N * 4);
  int* cnt = (int*)(wsb + off);          off = align256(off + (size_t)N * 4);
  int* offsets = (int*)(wsb + off);      off = align256(off + (size_t)N * 4);
  int* cursor = (int*)(wsb + off);       off = align256(off + (size_t)N * 4);
  int* bsum = (int*)(wsb + off);         off = align256(off + 1024);
  int* bexc = (int*)(wsb + off);         off = align256(off + 1024);
  float* partials = (float*)(wsb + off); off = align256(off + 256 * 128 * 4);
  float* st = (float*)(wsb + off);       off = align256(off + 512);
  ushort* h = (ushort*)(wsb + off);      off = align256(off + (size_t)N * HID * 2);
  int2* pack = (int2*)(wsb + off);       off = align256(off + (size_t)E * 8);

  const int NB = (N + 255) / 256;  // 196 <= 256

  hipMemsetAsync(cnt, 0, (size_t)N * 4, stream);
  k_deg_count<<<(E + 255) / 256, 256, 0, stream>>>(colp, cnt, E);
  k_scan1<<<NB, 256, 0, stream>>>(cnt, bsum, dis, N);
  k_scan2<<<1, 256, 0, stream>>>(bsum, bexc, NB);
  k_scan3<<<NB, 256, 0, stream>>>(cnt, bexc, offsets, cursor, N);
  k_place<<<(E + 255) / 256, 256, 0, stream>>>(rowp, colp, dis, cursor, pack, E);
  k_matmul<<<(N + 63) / 64, 256, 0, stream>>>(x, W, h, N);
  k_gather<<<(N + 3) / 4, 256, 0, stream>>>(offsets, cursor, pack, dis, h, bias,
                                            out, N);
  int total4 = N * (HID / 4);
  k_stats<<<256, 256, 0, stream>>>(out, partials, total4);
  k_reduce<<<1, 256, 0, stream>>>(partials, st, 256);
  k_finalize<<<256, 256, 0, stream>>>(out, st, gamma, beta, 1.0f / (float)N, total4);
}

// Round 4
// 161.742 us; speedup vs baseline: 5.2572x; 1.1952x over previous
//
#include <hip/hip_runtime.h>

constexpr int IND = 128;
constexpr int HID = 64;
constexpr float BN_EPS = 1e-5f;

static inline size_t align256(size_t x) { return (x + 255) & ~(size_t)255; }

__device__ inline ushort f2bf(float f) {
  uint u = __float_as_uint(f);
  uint r = (u + 0x7FFFu + ((u >> 16) & 1u)) >> 16;
  return (ushort)r;
}
__device__ inline float bf2f(ushort u) {
  return __uint_as_float(((uint)u) << 16);
}

// ---------- degree + per-edge rank within target group ----------
__global__ __launch_bounds__(256) void k_deg_count(const int* __restrict__ col,
                                                   int* __restrict__ cnt,
                                                   int* __restrict__ rank, int E) {
  int e = blockIdx.x * 256 + threadIdx.x;
  if (e < E) rank[e] = atomicAdd(&cnt[col[e]], 1);
}

// ---------- scan phase 1 (+ dis fused) ----------
__global__ __launch_bounds__(256) void k_scan1(const int* __restrict__ cnt,
                                               int* __restrict__ bsum,
                                               float* __restrict__ dis, int N) {
  __shared__ int ls[4];
  int i = blockIdx.x * 256 + threadIdx.x;
  int c = (i < N) ? cnt[i] : 0;
  if (i < N) dis[i] = rsqrtf((float)(c + 1));  // +1 self-loop
  int v = c;
#pragma unroll
  for (int s = 1; s < 64; s <<= 1) v += __shfl_xor(v, s);
  int wave = threadIdx.x >> 6;
  if ((threadIdx.x & 63) == 0) ls[wave] = v;
  __syncthreads();
  if (threadIdx.x == 0) bsum[blockIdx.x] = ls[0] + ls[1] + ls[2] + ls[3];
}

__global__ __launch_bounds__(256) void k_scan2(const int* __restrict__ bsum,
                                               int* __restrict__ bexc, int NB) {
  __shared__ int a[256];
  int tid = threadIdx.x;
  int v = (tid < NB) ? bsum[tid] : 0;
  a[tid] = v;
  __syncthreads();
#pragma unroll
  for (int s = 1; s < 256; s <<= 1) {
    int t = (tid >= s) ? a[tid - s] : 0;
    __syncthreads();
    a[tid] += t;
    __syncthreads();
  }
  bexc[tid] = a[tid] - v;  // exclusive
}

__global__ __launch_bounds__(256) void k_scan3(const int* __restrict__ cnt,
                                               const int* __restrict__ bexc,
                                               int* __restrict__ offsets, int N) {
  __shared__ int a[256];
  int tid = threadIdx.x;
  int i = blockIdx.x * 256 + tid;
  int v = (i < N) ? cnt[i] : 0;
  a[tid] = v;
  __syncthreads();
#pragma unroll
  for (int s = 1; s < 256; s <<= 1) {
    int t = (tid >= s) ? a[tid - s] : 0;
    __syncthreads();
    a[tid] += t;
    __syncthreads();
  }
  if (i < N) offsets[i] = a[tid] - v + bexc[blockIdx.x];
}

// ---------- placement (atomic-free): pack[offsets[col]+rank] = src ----------
__global__ __launch_bounds__(256) void k_place(const int* __restrict__ row,
                                               const int* __restrict__ col,
                                               const int* __restrict__ rank,
                                               const int* __restrict__ offsets,
                                               int* __restrict__ pack, int E) {
  int e = blockIdx.x * 256 + threadIdx.x;
  if (e >= E) return;
  int c = col[e];
  int pos = offsets[c] + rank[e];
  pack[pos] = row[e];
}

// ---------- g = dis .* (x @ W^T), stored bf16 ----------
__global__ __launch_bounds__(256) void k_matmul(const float* __restrict__ x,
                                                const float* __restrict__ W,
                                                const float* __restrict__ dis,
                                                ushort* __restrict__ g, int N) {
  __shared__ float ws[IND * HID];  // [k][c]
  __shared__ float xs[64 * IND];   // [n][k]
  const int tid = threadIdx.x;
  const int nb = blockIdx.x * 64;

  for (int id = tid; id < 2048; id += 256) {
    int c = id & 63;
    int k4 = (id >> 6) << 2;
    float4 w = *(const float4*)&W[c * IND + k4];
    ws[(k4 + 0) * HID + c] = w.x;
    ws[(k4 + 1) * HID + c] = w.y;
    ws[(k4 + 2) * HID + c] = w.z;
    ws[(k4 + 3) * HID + c] = w.w;
  }
  for (int id = tid; id < 2048; id += 256) {
    int n = id >> 5;
    int k4 = (id & 31) << 2;
    float4 v = make_float4(0.f, 0.f, 0.f, 0.f);
    if (nb + n < N) v = *(const float4*)&x[(size_t)(nb + n) * IND + k4];
    *(float4*)&xs[n * IND + k4] = v;
  }
  __syncthreads();

  const int c0 = (tid & 15) << 2;
  const int n0 = (tid >> 4) << 2;
  float acc[4][4] = {};
  for (int k = 0; k < IND; k += 4) {
    float4 w0 = *(const float4*)&ws[(k + 0) * HID + c0];
    float4 w1 = *(const float4*)&ws[(k + 1) * HID + c0];
    float4 w2 = *(const float4*)&ws[(k + 2) * HID + c0];
    float4 w3 = *(const float4*)&ws[(k + 3) * HID + c0];
#pragma unroll
    for (int j = 0; j < 4; ++j) {
      float4 xv = *(const float4*)&xs[(n0 + j) * IND + k];
      acc[j][0] += xv.x * w0.x + xv.y * w1.x + xv.z * w2.x + xv.w * w3.x;
      acc[j][1] += xv.x * w0.y + xv.y * w1.y + xv.z * w2.y + xv.w * w3.y;
      acc[j][2] += xv.x * w0.z + xv.y * w1.z + xv.z * w2.z + xv.w * w3.z;
      acc[j][3] += xv.x * w0.w + xv.y * w1.w + xv.z * w2.w + xv.w * w3.w;
    }
  }
#pragma unroll
  for (int j = 0; j < 4; ++j) {
    int node = nb + n0 + j;
    if (node < N) {
      float d = dis[node];
      ushort4 o;
      o.x = f2bf(d * acc[j][0]);
      o.y = f2bf(d * acc[j][1]);
      o.z = f2bf(d * acc[j][2]);
      o.w = f2bf(d * acc[j][3]);
      *(ushort4*)&g[(size_t)node * HID + c0] = o;
    }
  }
}

// ---------- gather: one wave per node, lane = channel, 8-edge ILP ----------
__global__ __launch_bounds__(256) void k_gather(const int* __restrict__ offsets,
                                                const int* __restrict__ pack,
                                                const float* __restrict__ dis,
                                                const ushort* __restrict__ g,
                                                const float* __restrict__ bias,
                                                float* __restrict__ out, int N,
                                                int E) {
  int wid = blockIdx.x * 4 + (threadIdx.x >> 6);
  int lane = threadIdx.x & 63;
  if (wid >= N) return;
  int off = __builtin_amdgcn_readfirstlane(offsets[wid]);
  int end = __builtin_amdgcn_readfirstlane((wid < N - 1) ? offsets[wid + 1] : E);
  float a0 = bf2f(g[(size_t)wid * HID + lane]);  // self-loop: +g[c]
  float a1 = 0.f, a2 = 0.f, a3 = 0.f;
  int j = off;
  for (; j + 8 <= end; j += 8) {
    int s0 = pack[j + 0], s1 = pack[j + 1], s2 = pack[j + 2], s3 = pack[j + 3];
    int s4 = pack[j + 4], s5 = pack[j + 5], s6 = pack[j + 6], s7 = pack[j + 7];
    float g0 = bf2f(g[(size_t)s0 * HID + lane]);
    float g1 = bf2f(g[(size_t)s1 * HID + lane]);
    float g2 = bf2f(g[(size_t)s2 * HID + lane]);
    float g3 = bf2f(g[(size_t)s3 * HID + lane]);
    float g4 = bf2f(g[(size_t)s4 * HID + lane]);
    float g5 = bf2f(g[(size_t)s5 * HID + lane]);
    float g6 = bf2f(g[(size_t)s6 * HID + lane]);
    float g7 = bf2f(g[(size_t)s7 * HID + lane]);
    a0 += g0; a1 += g1; a2 += g2; a3 += g3;
    a0 += g4; a1 += g5; a2 += g6; a3 += g7;
  }
  for (; j < end; ++j) {
    a0 += bf2f(g[(size_t)pack[j] * HID + lane]);
  }
  float acc = (a0 + a1) + (a2 + a3);
  out[(size_t)wid * HID + lane] = fmaxf(dis[wid] * acc + bias[lane], 0.f);
}

// ---------- BN stats over y (bias+relu already applied) ----------
__global__ __launch_bounds__(256) void k_stats(const float* __restrict__ y,
                                               float* __restrict__ partials,
                                               int total4) {
  __shared__ float ls[4][64];
  __shared__ float lq[4][64];
  int tid = threadIdx.x;
  int start = blockIdx.x * 256 + tid;
  int stride = gridDim.x * 256;
  int c0 = (tid & 15) << 2;
  float s0 = 0, s1 = 0, s2 = 0, s3 = 0, q0 = 0, q1 = 0, q2 = 0, q3 = 0;
  for (int i = start; i < total4; i += stride) {
    float4 v = *(const float4*)&y[(size_t)i * 4];
    s0 += v.x; s1 += v.y; s2 += v.z; s3 += v.w;
    q0 += v.x * v.x; q1 += v.y * v.y; q2 += v.z * v.z; q3 += v.w * v.w;
  }
  s0 += __shfl_xor(s0, 16); s0 += __shfl_xor(s0, 32);
  s1 += __shfl_xor(s1, 16); s1 += __shfl_xor(s1, 32);
  s2 += __shfl_xor(s2, 16); s2 += __shfl_xor(s2, 32);
  s3 += __shfl_xor(s3, 16); s3 += __shfl_xor(s3, 32);
  q0 += __shfl_xor(q0, 16); q0 += __shfl_xor(q0, 32);
  q1 += __shfl_xor(q1, 16); q1 += __shfl_xor(q1, 32);
  q2 += __shfl_xor(q2, 16); q2 += __shfl_xor(q2, 32);
  q3 += __shfl_xor(q3, 16); q3 += __shfl_xor(q3, 32);
  int wave = tid >> 6, lane = tid & 63;
  if (lane < 16) {
    ls[wave][c0 + 0] = s0; ls[wave][c0 + 1] = s1;
    ls[wave][c0 + 2] = s2; ls[wave][c0 + 3] = s3;
    lq[wave][c0 + 0] = q0; lq[wave][c0 + 1] = q1;
    lq[wave][c0 + 2] = q2; lq[wave][c0 + 3] = q3;
  }
  __syncthreads();
  if (tid < 64) {
    float s = ls[0][tid] + ls[1][tid] + ls[2][tid] + ls[3][tid];
    float q = lq[0][tid] + lq[1][tid] + lq[2][tid] + lq[3][tid];
    partials[blockIdx.x * 128 + tid] = s;
    partials[blockIdx.x * 128 + 64 + tid] = q;
  }
}

__global__ __launch_bounds__(256) void k_reduce(const float* __restrict__ partials,
                                                float* __restrict__ st, int nb) {
  __shared__ float tmp[256];
  int tid = threadIdx.x;
  int c = tid & 127;
  int half = tid >> 7;
  int hb = nb >> 1;
  float s = 0.f;
  for (int b = half * hb; b < (half + 1) * hb; ++b) s += partials[b * 128 + c];
  tmp[tid] = s;
  __syncthreads();
  if (tid < 128) st[tid] = tmp[tid] + tmp[tid + 128];
}

// ---------- BN normalize in place ----------
__global__ __launch_bounds__(256) void k_finalize(float* __restrict__ out,
                                                  const float* __restrict__ st,
                                                  const float* __restrict__ gamma,
                                                  const float* __restrict__ beta,
                                                  float invN, int total4) {
  int tid = threadIdx.x;
  int start = blockIdx.x * 256 + tid;
  int stride = gridDim.x * 256;
  int c0 = (tid & 15) << 2;
  float sc[4], sh[4];
#pragma unroll
  for (int j = 0; j < 4; ++j) {
    int c = c0 + j;
    float mean = st[c] * invN;
    float var = st[64 + c] * invN - mean * mean;
    float istd = rsqrtf(var + BN_EPS);
    float gm = gamma[c] * istd;
    sc[j] = gm;
    sh[j] = beta[c] - mean * gm;
  }
  for (int i = start; i < total4; i += stride) {
    float4 v = *(float4*)&out[(size_t)i * 4];
    float4 o = make_float4(v.x * sc[0] + sh[0], v.y * sc[1] + sh[1],
                           v.z * sc[2] + sh[2], v.w * sc[3] + sh[3]);
    *(float4*)&out[(size_t)i * 4] = o;
  }
}

extern "C" void kernel_launch(void* const* d_in, const int* in_sizes, int n_in,
                              void* d_out, int out_size, void* d_ws, size_t ws_size,
                              hipStream_t stream) {
  const float* x = (const float*)d_in[0];
  const int* ei = (const int*)d_in[1];
  const float* W = (const float*)d_in[3];
  const float* bias = (const float*)d_in[4];
  const float* gamma = (const float*)d_in[5];
  const float* beta = (const float*)d_in[6];
  const int N = in_sizes[0] / IND;
  const int E = in_sizes[1] / 2;
  const int* rowp = ei;      // sources
  const int* colp = ei + E;  // targets
  float* out = (float*)d_out;

  char* wsb = (char*)d_ws;
  size_t off = 0;
  float* dis = (float*)(wsb + off);      off = align256(off + (size_t)N * 4);
  int* cnt = (int*)(wsb + off);          off = align256(off + (size_t)N * 4);
  int* offsets = (int*)(wsb + off);      off = align256(off + (size_t)N * 4);
  int* rank = (int*)(wsb + off);         off = align256(off + (size_t)E * 4);
  int* bsum = (int*)(wsb + off);         off = align256(off + 1024);
  int* bexc = (int*)(wsb + off);         off = align256(off + 1024);
  float* partials = (float*)(wsb + off); off = align256(off + 256 * 128 * 4);
  float* st = (float*)(wsb + off);       off = align256(off + 512);
  ushort* g = (ushort*)(wsb + off);      off = align256(off + (size_t)N * HID * 2);
  int* pack = (int*)(wsb + off);         off = align256(off + (size_t)E * 4);

  const int NB = (N + 255) / 256;  // 196 <= 256

  hipMemsetAsync(cnt, 0, (size_t)N * 4, stream);
  k_deg_count<<<(E + 255) / 256, 256, 0, stream>>>(colp, cnt, rank, E);
  k_scan1<<<NB, 256, 0, stream>>>(cnt, bsum, dis, N);
  k_scan2<<<1, 256, 0, stream>>>(bsum, bexc, NB);
  k_scan3<<<NB, 256, 0, stream>>>(cnt, bexc, offsets, N);
  k_place<<<(E + 255) / 256, 256, 0, stream>>>(rowp, colp, rank, offsets, pack, E);
  k_matmul<<<(N + 63) / 64, 256, 0, stream>>>(x, W, dis, g, N);
  k_gather<<<(N + 3) / 4, 256, 0, stream>>>(offsets, pack, dis, g, bias, out, N, E);
  int total4 = N * (HID / 4);
  k_stats<<<256, 256, 0, stream>>>(out, partials, total4);
  k_reduce<<<1, 256, 0, stream>>>(partials, st, 256);
  k_finalize<<<256, 256, 0, stream>>>(out, st, gamma, beta, 1.0f / (float)N, total4);
}

// Round 5
// 161.685 us; speedup vs baseline: 5.2590x; 1.0003x over previous
//
#include <hip/hip_runtime.h>

constexpr int IND = 128;
constexpr int HID = 64;
constexpr float BN_EPS = 1e-5f;

static inline size_t align256(size_t x) { return (x + 255) & ~(size_t)255; }

__device__ inline ushort f2bf(float f) {
  uint u = __float_as_uint(f);
  uint r = (u + 0x7FFFu + ((u >> 16) & 1u)) >> 16;
  return (ushort)r;
}
__device__ inline float bf2f(ushort u) {
  return __uint_as_float(((uint)u) << 16);
}

// ---------- zero cnt (rocclr fillBuffer is latency-bound for small fills) ----------
__global__ __launch_bounds__(256) void k_zero(int4* __restrict__ p, int n4) {
  int i = blockIdx.x * 256 + threadIdx.x;
  if (i < n4) p[i] = make_int4(0, 0, 0, 0);
}

// ---------- degree + per-edge rank within target group ----------
__global__ __launch_bounds__(256) void k_deg_count(const int* __restrict__ col,
                                                   int* __restrict__ cnt,
                                                   int* __restrict__ rank, int E) {
  int e = blockIdx.x * 256 + threadIdx.x;
  if (e < E) rank[e] = atomicAdd(&cnt[col[e]], 1);
}

// ---------- scan phase 1 (+ dis fused) ----------
__global__ __launch_bounds__(256) void k_scan1(const int* __restrict__ cnt,
                                               int* __restrict__ bsum,
                                               float* __restrict__ dis, int N) {
  __shared__ int ls[4];
  int i = blockIdx.x * 256 + threadIdx.x;
  int c = (i < N) ? cnt[i] : 0;
  if (i < N) dis[i] = rsqrtf((float)(c + 1));  // +1 self-loop
  int v = c;
#pragma unroll
  for (int s = 1; s < 64; s <<= 1) v += __shfl_xor(v, s);
  int wave = threadIdx.x >> 6;
  if ((threadIdx.x & 63) == 0) ls[wave] = v;
  __syncthreads();
  if (threadIdx.x == 0) bsum[blockIdx.x] = ls[0] + ls[1] + ls[2] + ls[3];
}

__global__ __launch_bounds__(256) void k_scan2(const int* __restrict__ bsum,
                                               int* __restrict__ bexc, int NB) {
  __shared__ int a[256];
  int tid = threadIdx.x;
  int v = (tid < NB) ? bsum[tid] : 0;
  a[tid] = v;
  __syncthreads();
#pragma unroll
  for (int s = 1; s < 256; s <<= 1) {
    int t = (tid >= s) ? a[tid - s] : 0;
    __syncthreads();
    a[tid] += t;
    __syncthreads();
  }
  bexc[tid] = a[tid] - v;  // exclusive
}

__global__ __launch_bounds__(256) void k_scan3(const int* __restrict__ cnt,
                                               const int* __restrict__ bexc,
                                               int* __restrict__ offsets, int N) {
  __shared__ int a[256];
  int tid = threadIdx.x;
  int i = blockIdx.x * 256 + tid;
  int v = (i < N) ? cnt[i] : 0;
  a[tid] = v;
  __syncthreads();
#pragma unroll
  for (int s = 1; s < 256; s <<= 1) {
    int t = (tid >= s) ? a[tid - s] : 0;
    __syncthreads();
    a[tid] += t;
    __syncthreads();
  }
  if (i < N) offsets[i] = a[tid] - v + bexc[blockIdx.x];
}

// ---------- placement (atomic-free): pack[offsets[col]+rank] = src ----------
__global__ __launch_bounds__(256) void k_place(const int* __restrict__ row,
                                               const int* __restrict__ col,
                                               const int* __restrict__ rank,
                                               const int* __restrict__ offsets,
                                               int* __restrict__ pack, int E) {
  int e = blockIdx.x * 256 + threadIdx.x;
  if (e >= E) return;
  int c = col[e];
  int pos = offsets[c] + rank[e];
  pack[pos] = row[e];
}

// ---------- g = dis .* (x @ W^T), stored bf16 ----------
__global__ __launch_bounds__(256) void k_matmul(const float* __restrict__ x,
                                                const float* __restrict__ W,
                                                const float* __restrict__ dis,
                                                ushort* __restrict__ g, int N) {
  __shared__ float ws[IND * HID];  // [k][c]
  __shared__ float xs[64 * IND];   // [n][k]
  const int tid = threadIdx.x;
  const int nb = blockIdx.x * 64;

  for (int id = tid; id < 2048; id += 256) {
    int c = id & 63;
    int k4 = (id >> 6) << 2;
    float4 w = *(const float4*)&W[c * IND + k4];
    ws[(k4 + 0) * HID + c] = w.x;
    ws[(k4 + 1) * HID + c] = w.y;
    ws[(k4 + 2) * HID + c] = w.z;
    ws[(k4 + 3) * HID + c] = w.w;
  }
  for (int id = tid; id < 2048; id += 256) {
    int n = id >> 5;
    int k4 = (id & 31) << 2;
    float4 v = make_float4(0.f, 0.f, 0.f, 0.f);
    if (nb + n < N) v = *(const float4*)&x[(size_t)(nb + n) * IND + k4];
    *(float4*)&xs[n * IND + k4] = v;
  }
  __syncthreads();

  const int c0 = (tid & 15) << 2;
  const int n0 = (tid >> 4) << 2;
  float acc[4][4] = {};
  for (int k = 0; k < IND; k += 4) {
    float4 w0 = *(const float4*)&ws[(k + 0) * HID + c0];
    float4 w1 = *(const float4*)&ws[(k + 1) * HID + c0];
    float4 w2 = *(const float4*)&ws[(k + 2) * HID + c0];
    float4 w3 = *(const float4*)&ws[(k + 3) * HID + c0];
#pragma unroll
    for (int j = 0; j < 4; ++j) {
      float4 xv = *(const float4*)&xs[(n0 + j) * IND + k];
      acc[j][0] += xv.x * w0.x + xv.y * w1.x + xv.z * w2.x + xv.w * w3.x;
      acc[j][1] += xv.x * w0.y + xv.y * w1.y + xv.z * w2.y + xv.w * w3.y;
      acc[j][2] += xv.x * w0.z + xv.y * w1.z + xv.z * w2.z + xv.w * w3.z;
      acc[j][3] += xv.x * w0.w + xv.y * w1.w + xv.z * w2.w + xv.w * w3.w;
    }
  }
#pragma unroll
  for (int j = 0; j < 4; ++j) {
    int node = nb + n0 + j;
    if (node < N) {
      float d = dis[node];
      ushort4 o;
      o.x = f2bf(d * acc[j][0]);
      o.y = f2bf(d * acc[j][1]);
      o.z = f2bf(d * acc[j][2]);
      o.w = f2bf(d * acc[j][3]);
      *(ushort4*)&g[(size_t)node * HID + c0] = o;
    }
  }
}

// ---------- gather: one wave per node, lane = channel, 8-edge ILP ----------
__global__ __launch_bounds__(256) void k_gather(const int* __restrict__ offsets,
                                                const int* __restrict__ pack,
                                                const float* __restrict__ dis,
                                                const ushort* __restrict__ g,
                                                const float* __restrict__ bias,
                                                float* __restrict__ out, int N,
                                                int E) {
  int wid = blockIdx.x * 4 + (threadIdx.x >> 6);
  int lane = threadIdx.x & 63;
  if (wid >= N) return;
  int off = __builtin_amdgcn_readfirstlane(offsets[wid]);
  int end = __builtin_amdgcn_readfirstlane((wid < N - 1) ? offsets[wid + 1] : E);
  float a0 = bf2f(g[(size_t)wid * HID + lane]);  // self-loop: +g[c]
  float a1 = 0.f, a2 = 0.f, a3 = 0.f;
  int j = off;
  for (; j + 8 <= end; j += 8) {
    int s0 = pack[j + 0], s1 = pack[j + 1], s2 = pack[j + 2], s3 = pack[j + 3];
    int s4 = pack[j + 4], s5 = pack[j + 5], s6 = pack[j + 6], s7 = pack[j + 7];
    float g0 = bf2f(g[(size_t)s0 * HID + lane]);
    float g1 = bf2f(g[(size_t)s1 * HID + lane]);
    float g2 = bf2f(g[(size_t)s2 * HID + lane]);
    float g3 = bf2f(g[(size_t)s3 * HID + lane]);
    float g4 = bf2f(g[(size_t)s4 * HID + lane]);
    float g5 = bf2f(g[(size_t)s5 * HID + lane]);
    float g6 = bf2f(g[(size_t)s6 * HID + lane]);
    float g7 = bf2f(g[(size_t)s7 * HID + lane]);
    a0 += g0; a1 += g1; a2 += g2; a3 += g3;
    a0 += g4; a1 += g5; a2 += g6; a3 += g7;
  }
  for (; j < end; ++j) {
    a0 += bf2f(g[(size_t)pack[j] * HID + lane]);
  }
  float acc = (a0 + a1) + (a2 + a3);
  out[(size_t)wid * HID + lane] = fmaxf(dis[wid] * acc + bias[lane], 0.f);
}

// ---------- BN stats over y (bias+relu already applied) ----------
__global__ __launch_bounds__(256) void k_stats(const float* __restrict__ y,
                                               float* __restrict__ partials,
                                               int total4) {
  __shared__ float ls[4][64];
  __shared__ float lq[4][64];
  int tid = threadIdx.x;
  int start = blockIdx.x * 256 + tid;
  int stride = gridDim.x * 256;
  int c0 = (tid & 15) << 2;
  float s0 = 0, s1 = 0, s2 = 0, s3 = 0, q0 = 0, q1 = 0, q2 = 0, q3 = 0;
  for (int i = start; i < total4; i += stride) {
    float4 v = *(const float4*)&y[(size_t)i * 4];
    s0 += v.x; s1 += v.y; s2 += v.z; s3 += v.w;
    q0 += v.x * v.x; q1 += v.y * v.y; q2 += v.z * v.z; q3 += v.w * v.w;
  }
  s0 += __shfl_xor(s0, 16); s0 += __shfl_xor(s0, 32);
  s1 += __shfl_xor(s1, 16); s1 += __shfl_xor(s1, 32);
  s2 += __shfl_xor(s2, 16); s2 += __shfl_xor(s2, 32);
  s3 += __shfl_xor(s3, 16); s3 += __shfl_xor(s3, 32);
  q0 += __shfl_xor(q0, 16); q0 += __shfl_xor(q0, 32);
  q1 += __shfl_xor(q1, 16); q1 += __shfl_xor(q1, 32);
  q2 += __shfl_xor(q2, 16); q2 += __shfl_xor(q2, 32);
  q3 += __shfl_xor(q3, 16); q3 += __shfl_xor(q3, 32);
  int wave = tid >> 6, lane = tid & 63;
  if (lane < 16) {
    ls[wave][c0 + 0] = s0; ls[wave][c0 + 1] = s1;
    ls[wave][c0 + 2] = s2; ls[wave][c0 + 3] = s3;
    lq[wave][c0 + 0] = q0; lq[wave][c0 + 1] = q1;
    lq[wave][c0 + 2] = q2; lq[wave][c0 + 3] = q3;
  }
  __syncthreads();
  if (tid < 64) {
    float s = ls[0][tid] + ls[1][tid] + ls[2][tid] + ls[3][tid];
    float q = lq[0][tid] + lq[1][tid] + lq[2][tid] + lq[3][tid];
    partials[blockIdx.x * 128 + tid] = s;
    partials[blockIdx.x * 128 + 64 + tid] = q;
  }
}

__global__ __launch_bounds__(256) void k_reduce(const float* __restrict__ partials,
                                                float* __restrict__ st, int nb) {
  __shared__ float tmp[256];
  int tid = threadIdx.x;
  int c = tid & 127;
  int half = tid >> 7;
  int hb = nb >> 1;
  float s = 0.f;
  for (int b = half * hb; b < (half + 1) * hb; ++b) s += partials[b * 128 + c];
  tmp[tid] = s;
  __syncthreads();
  if (tid < 128) st[tid] = tmp[tid] + tmp[tid + 128];
}

// ---------- BN normalize in place ----------
__global__ __launch_bounds__(256) void k_finalize(float* __restrict__ out,
                                                  const float* __restrict__ st,
                                                  const float* __restrict__ gamma,
                                                  const float* __restrict__ beta,
                                                  float invN, int total4) {
  int tid = threadIdx.x;
  int start = blockIdx.x * 256 + tid;
  int stride = gridDim.x * 256;
  int c0 = (tid & 15) << 2;
  float sc[4], sh[4];
#pragma unroll
  for (int j = 0; j < 4; ++j) {
    int c = c0 + j;
    float mean = st[c] * invN;
    float var = st[64 + c] * invN - mean * mean;
    float istd = rsqrtf(var + BN_EPS);
    float gm = gamma[c] * istd;
    sc[j] = gm;
    sh[j] = beta[c] - mean * gm;
  }
  for (int i = start; i < total4; i += stride) {
    float4 v = *(float4*)&out[(size_t)i * 4];
    float4 o = make_float4(v.x * sc[0] + sh[0], v.y * sc[1] + sh[1],
                           v.z * sc[2] + sh[2], v.w * sc[3] + sh[3]);
    *(float4*)&out[(size_t)i * 4] = o;
  }
}

extern "C" void kernel_launch(void* const* d_in, const int* in_sizes, int n_in,
                              void* d_out, int out_size, void* d_ws, size_t ws_size,
                              hipStream_t stream) {
  const float* x = (const float*)d_in[0];
  const int* ei = (const int*)d_in[1];
  const float* W = (const float*)d_in[3];
  const float* bias = (const float*)d_in[4];
  const float* gamma = (const float*)d_in[5];
  const float* beta = (const float*)d_in[6];
  const int N = in_sizes[0] / IND;
  const int E = in_sizes[1] / 2;
  const int* rowp = ei;      // sources
  const int* colp = ei + E;  // targets
  float* out = (float*)d_out;

  char* wsb = (char*)d_ws;
  size_t off = 0;
  float* dis = (float*)(wsb + off);      off = align256(off + (size_t)N * 4);
  int* cnt = (int*)(wsb + off);          off = align256(off + (size_t)N * 4);
  int* offsets = (int*)(wsb + off);      off = align256(off + (size_t)N * 4);
  int* rank = (int*)(wsb + off);         off = align256(off + (size_t)E * 4);
  int* bsum = (int*)(wsb + off);         off = align256(off + 1024);
  int* bexc = (int*)(wsb + off);         off = align256(off + 1024);
  float* partials = (float*)(wsb + off); off = align256(off + 256 * 128 * 4);
  float* st = (float*)(wsb + off);       off = align256(off + 512);
  ushort* g = (ushort*)(wsb + off);      off = align256(off + (size_t)N * HID * 2);
  int* pack = (int*)(wsb + off);         off = align256(off + (size_t)E * 4);

  const int NB = (N + 255) / 256;  // 196 <= 256

  // zero cnt with our own kernel: hipMemsetAsync -> rocclr fillBuffer was
  // latency-bound at 44 us for a 200 KB fill (R4 profile)
  int n4 = (N + 3) / 4;
  k_zero<<<(n4 + 255) / 256, 256, 0, stream>>>((int4*)cnt, n4);
  k_deg_count<<<(E + 255) / 256, 256, 0, stream>>>(colp, cnt, rank, E);
  k_scan1<<<NB, 256, 0, stream>>>(cnt, bsum, dis, N);
  k_scan2<<<1, 256, 0, stream>>>(bsum, bexc, NB);
  k_scan3<<<NB, 256, 0, stream>>>(cnt, bexc, offsets, N);
  k_place<<<(E + 255) / 256, 256, 0, stream>>>(rowp, colp, rank, offsets, pack, E);
  k_matmul<<<(N + 63) / 64, 256, 0, stream>>>(x, W, dis, g, N);
  k_gather<<<(N + 3) / 4, 256, 0, stream>>>(offsets, pack, dis, g, bias, out, N, E);
  int total4 = N * (HID / 4);
  k_stats<<<256, 256, 0, stream>>>(out, partials, total4);
  k_reduce<<<1, 256, 0, stream>>>(partials, st, 256);
  k_finalize<<<256, 256, 0, stream>>>(out, st, gamma, beta, 1.0f / (float)N, total4);
}

// Round 6
// 159.572 us; speedup vs baseline: 5.3287x; 1.0132x over previous
//
#include <hip/hip_runtime.h>

constexpr int IND = 128;
constexpr int HID = 64;
constexpr float BN_EPS = 1e-5f;

static inline size_t align256(size_t x) { return (x + 255) & ~(size_t)255; }

__device__ inline ushort f2bf(float f) {
  uint u = __float_as_uint(f);
  uint r = (u + 0x7FFFu + ((u >> 16) & 1u)) >> 16;
  return (ushort)r;
}
__device__ inline float bf2f(ushort u) {
  return __uint_as_float(((uint)u) << 16);
}

// ---------- zero cnt ----------
__global__ __launch_bounds__(256) void k_zero(int4* __restrict__ p, int n4) {
  int i = blockIdx.x * 256 + threadIdx.x;
  if (i < n4) p[i] = make_int4(0, 0, 0, 0);
}

// ---------- degree + per-edge rank within target group ----------
__global__ __launch_bounds__(256) void k_deg_count(const int* __restrict__ col,
                                                   int* __restrict__ cnt,
                                                   int* __restrict__ rank, int E) {
  int e = blockIdx.x * 256 + threadIdx.x;
  if (e < E) rank[e] = atomicAdd(&cnt[col[e]], 1);
}

// ---------- scanA: dis + LOCAL exclusive scan -> offsets, block sums -> bsum ----------
__global__ __launch_bounds__(256) void k_scanA(const int* __restrict__ cnt,
                                               int* __restrict__ bsum,
                                               int* __restrict__ offsets,
                                               float* __restrict__ dis, int N) {
  __shared__ int a[256];
  int tid = threadIdx.x;
  int i = blockIdx.x * 256 + tid;
  int v = (i < N) ? cnt[i] : 0;
  if (i < N) dis[i] = rsqrtf((float)(v + 1));  // +1 self-loop
  a[tid] = v;
  __syncthreads();
#pragma unroll
  for (int s = 1; s < 256; s <<= 1) {
    int t = (tid >= s) ? a[tid - s] : 0;
    __syncthreads();
    a[tid] += t;
    __syncthreads();
  }
  if (i < N) offsets[i] = a[tid] - v;  // local exclusive
  if (tid == 255) bsum[blockIdx.x] = a[255];
}

// ---------- scan2: exclusive scan of block sums ----------
__global__ __launch_bounds__(256) void k_scan2(const int* __restrict__ bsum,
                                               int* __restrict__ bexc, int NB) {
  __shared__ int a[256];
  int tid = threadIdx.x;
  int v = (tid < NB) ? bsum[tid] : 0;
  a[tid] = v;
  __syncthreads();
#pragma unroll
  for (int s = 1; s < 256; s <<= 1) {
    int t = (tid >= s) ? a[tid - s] : 0;
    __syncthreads();
    a[tid] += t;
    __syncthreads();
  }
  bexc[tid] = a[tid] - v;  // exclusive
}

// ---------- placement (atomic-free) ----------
__global__ __launch_bounds__(256) void k_place(const int* __restrict__ row,
                                               const int* __restrict__ col,
                                               const int* __restrict__ rank,
                                               const int* __restrict__ offsets,
                                               const int* __restrict__ bexc,
                                               int* __restrict__ pack, int E) {
  int e = blockIdx.x * 256 + threadIdx.x;
  if (e >= E) return;
  int c = col[e];
  int pos = offsets[c] + bexc[c >> 8] + rank[e];
  pack[pos] = row[e];
}

// ---------- g = dis .* (x @ W^T), stored bf16 ----------
__global__ __launch_bounds__(256) void k_matmul(const float* __restrict__ x,
                                                const float* __restrict__ W,
                                                const float* __restrict__ dis,
                                                ushort* __restrict__ g, int N) {
  __shared__ float ws[IND * HID];  // [k][c]
  __shared__ float xs[64 * IND];   // [n][k]
  const int tid = threadIdx.x;
  const int nb = blockIdx.x * 64;

  for (int id = tid; id < 2048; id += 256) {
    int c = id & 63;
    int k4 = (id >> 6) << 2;
    float4 w = *(const float4*)&W[c * IND + k4];
    ws[(k4 + 0) * HID + c] = w.x;
    ws[(k4 + 1) * HID + c] = w.y;
    ws[(k4 + 2) * HID + c] = w.z;
    ws[(k4 + 3) * HID + c] = w.w;
  }
  for (int id = tid; id < 2048; id += 256) {
    int n = id >> 5;
    int k4 = (id & 31) << 2;
    float4 v = make_float4(0.f, 0.f, 0.f, 0.f);
    if (nb + n < N) v = *(const float4*)&x[(size_t)(nb + n) * IND + k4];
    *(float4*)&xs[n * IND + k4] = v;
  }
  __syncthreads();

  const int c0 = (tid & 15) << 2;
  const int n0 = (tid >> 4) << 2;
  float acc[4][4] = {};
  for (int k = 0; k < IND; k += 4) {
    float4 w0 = *(const float4*)&ws[(k + 0) * HID + c0];
    float4 w1 = *(const float4*)&ws[(k + 1) * HID + c0];
    float4 w2 = *(const float4*)&ws[(k + 2) * HID + c0];
    float4 w3 = *(const float4*)&ws[(k + 3) * HID + c0];
#pragma unroll
    for (int j = 0; j < 4; ++j) {
      float4 xv = *(const float4*)&xs[(n0 + j) * IND + k];
      acc[j][0] += xv.x * w0.x + xv.y * w1.x + xv.z * w2.x + xv.w * w3.x;
      acc[j][1] += xv.x * w0.y + xv.y * w1.y + xv.z * w2.y + xv.w * w3.y;
      acc[j][2] += xv.x * w0.z + xv.y * w1.z + xv.z * w2.z + xv.w * w3.z;
      acc[j][3] += xv.x * w0.w + xv.y * w1.w + xv.z * w2.w + xv.w * w3.w;
    }
  }
#pragma unroll
  for (int j = 0; j < 4; ++j) {
    int node = nb + n0 + j;
    if (node < N) {
      float d = dis[node];
      ushort4 o;
      o.x = f2bf(d * acc[j][0]);
      o.y = f2bf(d * acc[j][1]);
      o.z = f2bf(d * acc[j][2]);
      o.w = f2bf(d * acc[j][3]);
      *(ushort4*)&g[(size_t)node * HID + c0] = o;
    }
  }
}

// ---------- gather: wave per node, lane = channel, 8-edge ILP; writes bf16 y ----------
__global__ __launch_bounds__(256) void k_gather(const int* __restrict__ offsets,
                                                const int* __restrict__ bexc,
                                                const int* __restrict__ pack,
                                                const float* __restrict__ dis,
                                                const ushort* __restrict__ g,
                                                const float* __restrict__ bias,
                                                ushort* __restrict__ ybf, int N,
                                                int E) {
  int wid = blockIdx.x * 4 + (threadIdx.x >> 6);
  int lane = threadIdx.x & 63;
  if (wid >= N) return;
  int off = __builtin_amdgcn_readfirstlane(offsets[wid] + bexc[wid >> 8]);
  int end = __builtin_amdgcn_readfirstlane(
      (wid < N - 1) ? offsets[wid + 1] + bexc[(wid + 1) >> 8] : E);
  float a0 = bf2f(g[(size_t)wid * HID + lane]);  // self-loop: +g[c]
  float a1 = 0.f, a2 = 0.f, a3 = 0.f;
  int j = off;
  for (; j + 8 <= end; j += 8) {
    int s0 = pack[j + 0], s1 = pack[j + 1], s2 = pack[j + 2], s3 = pack[j + 3];
    int s4 = pack[j + 4], s5 = pack[j + 5], s6 = pack[j + 6], s7 = pack[j + 7];
    float g0 = bf2f(g[(size_t)s0 * HID + lane]);
    float g1 = bf2f(g[(size_t)s1 * HID + lane]);
    float g2 = bf2f(g[(size_t)s2 * HID + lane]);
    float g3 = bf2f(g[(size_t)s3 * HID + lane]);
    float g4 = bf2f(g[(size_t)s4 * HID + lane]);
    float g5 = bf2f(g[(size_t)s5 * HID + lane]);
    float g6 = bf2f(g[(size_t)s6 * HID + lane]);
    float g7 = bf2f(g[(size_t)s7 * HID + lane]);
    a0 += g0; a1 += g1; a2 += g2; a3 += g3;
    a0 += g4; a1 += g5; a2 += g6; a3 += g7;
  }
  for (; j < end; ++j) {
    a0 += bf2f(g[(size_t)pack[j] * HID + lane]);
  }
  float acc = (a0 + a1) + (a2 + a3);
  float y = fmaxf(dis[wid] * acc + bias[lane], 0.f);
  ybf[(size_t)wid * HID + lane] = f2bf(y);
}

// ---------- BN stats over bf16 y: per-block partials ----------
__global__ __launch_bounds__(256) void k_stats(const ushort* __restrict__ y,
                                               float* __restrict__ partials,
                                               int total8) {
  __shared__ float ls[4][64];
  __shared__ float lq[4][64];
  int tid = threadIdx.x;
  int start = blockIdx.x * 256 + tid;
  int stride = gridDim.x * 256;       // 65536, %8==0
  int c0 = (tid & 7) << 3;            // 8 channels per thread
  float s[8] = {}, q[8] = {};
  for (int i = start; i < total8; i += stride) {
    uint4 v = *(const uint4*)&y[(size_t)i * 8];
    float f0 = bf2f((ushort)(v.x & 0xffff)), f1 = bf2f((ushort)(v.x >> 16));
    float f2 = bf2f((ushort)(v.y & 0xffff)), f3 = bf2f((ushort)(v.y >> 16));
    float f4 = bf2f((ushort)(v.z & 0xffff)), f5 = bf2f((ushort)(v.z >> 16));
    float f6 = bf2f((ushort)(v.w & 0xffff)), f7 = bf2f((ushort)(v.w >> 16));
    s[0] += f0; q[0] += f0 * f0; s[1] += f1; q[1] += f1 * f1;
    s[2] += f2; q[2] += f2 * f2; s[3] += f3; q[3] += f3 * f3;
    s[4] += f4; q[4] += f4 * f4; s[5] += f5; q[5] += f5 * f5;
    s[6] += f6; q[6] += f6 * f6; s[7] += f7; q[7] += f7 * f7;
  }
#pragma unroll
  for (int k = 0; k < 8; ++k) {
    s[k] += __shfl_xor(s[k], 8);  s[k] += __shfl_xor(s[k], 16);
    s[k] += __shfl_xor(s[k], 32);
    q[k] += __shfl_xor(q[k], 8);  q[k] += __shfl_xor(q[k], 16);
    q[k] += __shfl_xor(q[k], 32);
  }
  int wave = tid >> 6, lane = tid & 63;
  if (lane < 8) {
#pragma unroll
    for (int k = 0; k < 8; ++k) {
      ls[wave][c0 + k] = s[k];
      lq[wave][c0 + k] = q[k];
    }
  }
  __syncthreads();
  if (tid < 64) {
    float ss = ls[0][tid] + ls[1][tid] + ls[2][tid] + ls[3][tid];
    float qq = lq[0][tid] + lq[1][tid] + lq[2][tid] + lq[3][tid];
    partials[blockIdx.x * 128 + tid] = ss;
    partials[blockIdx.x * 128 + 64 + tid] = qq;
  }
}

// ---------- finalize: self-reduce partials, normalize bf16 y -> fp32 out ----------
__global__ __launch_bounds__(256) void k_finalize(const ushort* __restrict__ y,
                                                  const float* __restrict__ partials,
                                                  const float* __restrict__ gamma,
                                                  const float* __restrict__ beta,
                                                  float* __restrict__ out,
                                                  float invN, int total8, int pb) {
  __shared__ float tmp[256];
  __shared__ float red[128];
  int tid = threadIdx.x;
  // redundant per-block reduction of partials[pb][128]
  {
    int c = tid & 127;
    int half = tid >> 7;
    int hb = pb >> 1;
    float s = 0.f;
    for (int b = half * hb; b < (half + 1) * hb; ++b) s += partials[b * 128 + c];
    tmp[tid] = s;
    __syncthreads();
    if (tid < 128) red[tid] = tmp[tid] + tmp[tid + 128];
    __syncthreads();
  }
  int c0 = (tid & 7) << 3;
  float sc[8], sh[8];
#pragma unroll
  for (int k = 0; k < 8; ++k) {
    int c = c0 + k;
    float mean = red[c] * invN;
    float var = red[64 + c] * invN - mean * mean;
    float istd = rsqrtf(var + BN_EPS);
    float gm = gamma[c] * istd;
    sc[k] = gm;
    sh[k] = beta[c] - mean * gm;
  }
  int start = blockIdx.x * 256 + tid;
  int stride = gridDim.x * 256;  // %8==0
  for (int i = start; i < total8; i += stride) {
    uint4 v = *(const uint4*)&y[(size_t)i * 8];
    float f0 = bf2f((ushort)(v.x & 0xffff)), f1 = bf2f((ushort)(v.x >> 16));
    float f2 = bf2f((ushort)(v.y & 0xffff)), f3 = bf2f((ushort)(v.y >> 16));
    float f4 = bf2f((ushort)(v.z & 0xffff)), f5 = bf2f((ushort)(v.z >> 16));
    float f6 = bf2f((ushort)(v.w & 0xffff)), f7 = bf2f((ushort)(v.w >> 16));
    float4 o0 = make_float4(f0 * sc[0] + sh[0], f1 * sc[1] + sh[1],
                            f2 * sc[2] + sh[2], f3 * sc[3] + sh[3]);
    float4 o1 = make_float4(f4 * sc[4] + sh[4], f5 * sc[5] + sh[5],
                            f6 * sc[6] + sh[6], f7 * sc[7] + sh[7]);
    *(float4*)&out[(size_t)i * 8] = o0;
    *(float4*)&out[(size_t)i * 8 + 4] = o1;
  }
}

extern "C" void kernel_launch(void* const* d_in, const int* in_sizes, int n_in,
                              void* d_out, int out_size, void* d_ws, size_t ws_size,
                              hipStream_t stream) {
  const float* x = (const float*)d_in[0];
  const int* ei = (const int*)d_in[1];
  const float* W = (const float*)d_in[3];
  const float* bias = (const float*)d_in[4];
  const float* gamma = (const float*)d_in[5];
  const float* beta = (const float*)d_in[6];
  const int N = in_sizes[0] / IND;
  const int E = in_sizes[1] / 2;
  const int* rowp = ei;      // sources
  const int* colp = ei + E;  // targets
  float* out = (float*)d_out;

  char* wsb = (char*)d_ws;
  size_t off = 0;
  float* dis = (float*)(wsb + off);      off = align256(off + (size_t)N * 4);
  int* cnt = (int*)(wsb + off);          off = align256(off + (size_t)N * 4);
  int* offsets = (int*)(wsb + off);      off = align256(off + (size_t)N * 4);
  int* rank = (int*)(wsb + off);         off = align256(off + (size_t)E * 4);
  int* bsum = (int*)(wsb + off);         off = align256(off + 1024);
  int* bexc = (int*)(wsb + off);         off = align256(off + 1024);
  float* partials = (float*)(wsb + off); off = align256(off + 256 * 128 * 4);
  ushort* g = (ushort*)(wsb + off);      off = align256(off + (size_t)N * HID * 2);
  ushort* ybf = (ushort*)(wsb + off);    off = align256(off + (size_t)N * HID * 2);
  int* pack = (int*)(wsb + off);         off = align256(off + (size_t)E * 4);

  const int NB = (N + 255) / 256;  // 196 <= 256

  int n4 = (N + 3) / 4;
  k_zero<<<(n4 + 255) / 256, 256, 0, stream>>>((int4*)cnt, n4);
  k_deg_count<<<(E + 255) / 256, 256, 0, stream>>>(colp, cnt, rank, E);
  k_scanA<<<NB, 256, 0, stream>>>(cnt, bsum, offsets, dis, N);
  k_scan2<<<1, 256, 0, stream>>>(bsum, bexc, NB);
  k_place<<<(E + 255) / 256, 256, 0, stream>>>(rowp, colp, rank, offsets, bexc,
                                               pack, E);
  k_matmul<<<(N + 63) / 64, 256, 0, stream>>>(x, W, dis, g, N);
  k_gather<<<(N + 3) / 4, 256, 0, stream>>>(offsets, bexc, pack, dis, g, bias,
                                            ybf, N, E);
  int total8 = N * (HID / 8);
  k_stats<<<256, 256, 0, stream>>>(ybf, partials, total8);
  k_finalize<<<256, 256, 0, stream>>>(ybf, partials, gamma, beta, out,
                                      1.0f / (float)N, total8, 256);
}

// Round 7
// 145.645 us; speedup vs baseline: 5.8382x; 1.0956x over previous
//
#include <hip/hip_runtime.h>

constexpr int IND = 128;
constexpr int HID = 64;
constexpr float BN_EPS = 1e-5f;

static inline size_t align256(size_t x) { return (x + 255) & ~(size_t)255; }

__device__ inline ushort f2bf(float f) {
  uint u = __float_as_uint(f);
  uint r = (u + 0x7FFFu + ((u >> 16) & 1u)) >> 16;
  return (ushort)r;
}
__device__ inline float bf2f(ushort u) {
  return __uint_as_float(((uint)u) << 16);
}

// ---------- init: zero cnt, prefill pack with dummy N, zero g row N ----------
__global__ __launch_bounds__(256) void k_init(int4* __restrict__ cnt4, int n4,
                                              int4* __restrict__ pack4, int p4,
                                              uint4* __restrict__ grow, int dummy) {
  int i = blockIdx.x * 256 + threadIdx.x;
  int stride = gridDim.x * 256;
  int4 dv = make_int4(dummy, dummy, dummy, dummy);
  for (int j = i; j < p4; j += stride) pack4[j] = dv;
  for (int j = i; j < n4; j += stride) cnt4[j] = make_int4(0, 0, 0, 0);
  if (i < 8) grow[i] = make_uint4(0, 0, 0, 0);  // g row N (dummy) = 0
}

// ---------- degree + rank, 4 edges/thread ----------
__global__ __launch_bounds__(256) void k_deg_count(const int* __restrict__ col,
                                                   int* __restrict__ cnt,
                                                   int* __restrict__ rank, int E4) {
  int i = blockIdx.x * 256 + threadIdx.x;
  if (i >= E4) return;
  int4 c = ((const int4*)col)[i];
  int4 r;
  r.x = atomicAdd(&cnt[c.x], 1);
  r.y = atomicAdd(&cnt[c.y], 1);
  r.z = atomicAdd(&cnt[c.z], 1);
  r.w = atomicAdd(&cnt[c.w], 1);
  ((int4*)rank)[i] = r;
}

// ---------- scanA: dis + local exclusive scan of PADDED counts ----------
__global__ __launch_bounds__(256) void k_scanA(const int* __restrict__ cnt,
                                               int* __restrict__ bsum,
                                               int* __restrict__ offsets,
                                               float* __restrict__ dis, int N) {
  __shared__ int a[256];
  int tid = threadIdx.x;
  int i = blockIdx.x * 256 + tid;
  int v = (i < N) ? cnt[i] : 0;
  if (i < N) dis[i] = rsqrtf((float)(v + 1));  // +1 self-loop
  int pv = (v + 7) & ~7;                       // pad to %8 for full-ILP gather
  a[tid] = pv;
  __syncthreads();
#pragma unroll
  for (int s = 1; s < 256; s <<= 1) {
    int t = (tid >= s) ? a[tid - s] : 0;
    __syncthreads();
    a[tid] += t;
    __syncthreads();
  }
  if (i < N) offsets[i] = a[tid] - pv;  // local exclusive (padded)
  if (tid == 255) bsum[blockIdx.x] = a[255];
}

// ---------- fused: blocks [0,MMB) matmul (g = dis.*xW^T bf16); rest place ----------
__global__ __launch_bounds__(256) void k_fused(
    const float* __restrict__ x, const float* __restrict__ W,
    const float* __restrict__ dis, ushort* __restrict__ g,
    const int* __restrict__ row, const int* __restrict__ col,
    const int* __restrict__ rank, const int* __restrict__ offsets,
    const int* __restrict__ bsum, int* __restrict__ gbexc,
    int* __restrict__ pack, int N, int E, int MMB, int PB, int NB) {
  __shared__ float ws[IND * HID];  // 32KB: matmul W^T stage; place aliases
  int tid = threadIdx.x;
  if ((int)blockIdx.x < MMB) {
    // ---- matmul role ----
    int nb = blockIdx.x * 64;
    for (int id = tid; id < 2048; id += 256) {
      int c = id & 63;
      int k4 = (id >> 6) << 2;
      float4 w = *(const float4*)&W[c * IND + k4];
      ws[(k4 + 0) * HID + c] = w.x;
      ws[(k4 + 1) * HID + c] = w.y;
      ws[(k4 + 2) * HID + c] = w.z;
      ws[(k4 + 3) * HID + c] = w.w;
    }
    __syncthreads();
    const int c0 = (tid & 15) << 2;
    const int n0 = (tid >> 4) << 2;
    const float* xr[4];
#pragma unroll
    for (int j = 0; j < 4; ++j) {
      int node = nb + n0 + j;
      if (node > N - 1) node = N - 1;  // clamp loads; store is guarded
      xr[j] = x + (size_t)node * IND;
    }
    float acc[4][4] = {};
    for (int k = 0; k < IND; k += 4) {
      float4 xv0 = *(const float4*)(xr[0] + k);
      float4 xv1 = *(const float4*)(xr[1] + k);
      float4 xv2 = *(const float4*)(xr[2] + k);
      float4 xv3 = *(const float4*)(xr[3] + k);
      float4 w0 = *(const float4*)&ws[(k + 0) * HID + c0];
      float4 w1 = *(const float4*)&ws[(k + 1) * HID + c0];
      float4 w2 = *(const float4*)&ws[(k + 2) * HID + c0];
      float4 w3 = *(const float4*)&ws[(k + 3) * HID + c0];
      acc[0][0] += xv0.x * w0.x + xv0.y * w1.x + xv0.z * w2.x + xv0.w * w3.x;
      acc[0][1] += xv0.x * w0.y + xv0.y * w1.y + xv0.z * w2.y + xv0.w * w3.y;
      acc[0][2] += xv0.x * w0.z + xv0.y * w1.z + xv0.z * w2.z + xv0.w * w3.z;
      acc[0][3] += xv0.x * w0.w + xv0.y * w1.w + xv0.z * w2.w + xv0.w * w3.w;
      acc[1][0] += xv1.x * w0.x + xv1.y * w1.x + xv1.z * w2.x + xv1.w * w3.x;
      acc[1][1] += xv1.x * w0.y + xv1.y * w1.y + xv1.z * w2.y + xv1.w * w3.y;
      acc[1][2] += xv1.x * w0.z + xv1.y * w1.z + xv1.z * w2.z + xv1.w * w3.z;
      acc[1][3] += xv1.x * w0.w + xv1.y * w1.w + xv1.z * w2.w + xv1.w * w3.w;
      acc[2][0] += xv2.x * w0.x + xv2.y * w1.x + xv2.z * w2.x + xv2.w * w3.x;
      acc[2][1] += xv2.x * w0.y + xv2.y * w1.y + xv2.z * w2.y + xv2.w * w3.y;
      acc[2][2] += xv2.x * w0.z + xv2.y * w1.z + xv2.z * w2.z + xv2.w * w3.z;
      acc[2][3] += xv2.x * w0.w + xv2.y * w1.w + xv2.z * w2.w + xv2.w * w3.w;
      acc[3][0] += xv3.x * w0.x + xv3.y * w1.x + xv3.z * w2.x + xv3.w * w3.x;
      acc[3][1] += xv3.x * w0.y + xv3.y * w1.y + xv3.z * w2.y + xv3.w * w3.y;
      acc[3][2] += xv3.x * w0.z + xv3.y * w1.z + xv3.z * w2.z + xv3.w * w3.z;
      acc[3][3] += xv3.x * w0.w + xv3.y * w1.w + xv3.z * w2.w + xv3.w * w3.w;
    }
#pragma unroll
    for (int j = 0; j < 4; ++j) {
      int node = nb + n0 + j;
      if (node < N) {
        float d = dis[node];
        ushort4 o;
        o.x = f2bf(d * acc[j][0]);
        o.y = f2bf(d * acc[j][1]);
        o.z = f2bf(d * acc[j][2]);
        o.w = f2bf(d * acc[j][3]);
        *(ushort4*)&g[(size_t)node * HID + c0] = o;
      }
    }
  } else {
    // ---- place role: per-block redundant scan of bsum -> bexc in LDS ----
    int* sa = (int*)ws;
    int* sb = sa + 256;
    int v = (tid < NB) ? bsum[tid] : 0;
    sa[tid] = v;
    __syncthreads();
#pragma unroll
    for (int s = 1; s < 256; s <<= 1) {
      int t = (tid >= s) ? sa[tid - s] : 0;
      __syncthreads();
      sa[tid] += t;
      __syncthreads();
    }
    sb[tid] = sa[tid] - v;  // exclusive
    if ((int)blockIdx.x == MMB) {
      gbexc[tid] = sa[tid] - v;
      if (tid == 255) gbexc[256] = sa[255];  // total (sentinel for gather)
    }
    __syncthreads();
    int pb = blockIdx.x - MMB;
    for (int e = pb * 256 + tid; e < E; e += PB * 256) {
      int c = col[e];
      int pos = offsets[c] + sb[c >> 8] + rank[e];
      pack[pos] = row[e];
    }
  }
}

// ---------- gather: wave per node, lane = channel, padded full 8-ILP ----------
__global__ __launch_bounds__(256) void k_gather(const int* __restrict__ offsets,
                                                const int* __restrict__ gbexc,
                                                const int* __restrict__ pack,
                                                const float* __restrict__ dis,
                                                const ushort* __restrict__ g,
                                                const float* __restrict__ bias,
                                                ushort* __restrict__ ybf, int N) {
  int wid = blockIdx.x * 4 + (threadIdx.x >> 6);
  int lane = threadIdx.x & 63;
  if (wid >= N) return;
  int off = __builtin_amdgcn_readfirstlane(offsets[wid] + gbexc[wid >> 8]);
  int end = __builtin_amdgcn_readfirstlane(
      (wid < N - 1) ? offsets[wid + 1] + gbexc[(wid + 1) >> 8] : gbexc[256]);
  float a0 = bf2f(g[(size_t)wid * HID + lane]);  // self-loop: +g[c]
  float a1 = 0.f, a2 = 0.f, a3 = 0.f;
  for (int j = off; j < end; j += 8) {  // end-off always %8 == 0 (padded)
    int s0 = pack[j + 0], s1 = pack[j + 1], s2 = pack[j + 2], s3 = pack[j + 3];
    int s4 = pack[j + 4], s5 = pack[j + 5], s6 = pack[j + 6], s7 = pack[j + 7];
    float g0 = bf2f(g[(size_t)s0 * HID + lane]);
    float g1 = bf2f(g[(size_t)s1 * HID + lane]);
    float g2 = bf2f(g[(size_t)s2 * HID + lane]);
    float g3 = bf2f(g[(size_t)s3 * HID + lane]);
    float g4 = bf2f(g[(size_t)s4 * HID + lane]);
    float g5 = bf2f(g[(size_t)s5 * HID + lane]);
    float g6 = bf2f(g[(size_t)s6 * HID + lane]);
    float g7 = bf2f(g[(size_t)s7 * HID + lane]);
    a0 += g0; a1 += g1; a2 += g2; a3 += g3;
    a0 += g4; a1 += g5; a2 += g6; a3 += g7;
  }
  float acc = (a0 + a1) + (a2 + a3);
  float y = fmaxf(dis[wid] * acc + bias[lane], 0.f);
  ybf[(size_t)wid * HID + lane] = f2bf(y);
}

// ---------- BN stats over bf16 y: per-block partials ----------
__global__ __launch_bounds__(256) void k_stats(const ushort* __restrict__ y,
                                               float* __restrict__ partials,
                                               int total8) {
  __shared__ float ls[4][64];
  __shared__ float lq[4][64];
  int tid = threadIdx.x;
  int start = blockIdx.x * 256 + tid;
  int stride = gridDim.x * 256;  // 65536, %8==0
  int c0 = (tid & 7) << 3;       // 8 channels per thread
  float s[8] = {}, q[8] = {};
  for (int i = start; i < total8; i += stride) {
    uint4 v = *(const uint4*)&y[(size_t)i * 8];
    float f0 = bf2f((ushort)(v.x & 0xffff)), f1 = bf2f((ushort)(v.x >> 16));
    float f2 = bf2f((ushort)(v.y & 0xffff)), f3 = bf2f((ushort)(v.y >> 16));
    float f4 = bf2f((ushort)(v.z & 0xffff)), f5 = bf2f((ushort)(v.z >> 16));
    float f6 = bf2f((ushort)(v.w & 0xffff)), f7 = bf2f((ushort)(v.w >> 16));
    s[0] += f0; q[0] += f0 * f0; s[1] += f1; q[1] += f1 * f1;
    s[2] += f2; q[2] += f2 * f2; s[3] += f3; q[3] += f3 * f3;
    s[4] += f4; q[4] += f4 * f4; s[5] += f5; q[5] += f5 * f5;
    s[6] += f6; q[6] += f6 * f6; s[7] += f7; q[7] += f7 * f7;
  }
#pragma unroll
  for (int k = 0; k < 8; ++k) {
    s[k] += __shfl_xor(s[k], 8);  s[k] += __shfl_xor(s[k], 16);
    s[k] += __shfl_xor(s[k], 32);
    q[k] += __shfl_xor(q[k], 8);  q[k] += __shfl_xor(q[k], 16);
    q[k] += __shfl_xor(q[k], 32);
  }
  int wave = tid >> 6, lane = tid & 63;
  if (lane < 8) {
#pragma unroll
    for (int k = 0; k < 8; ++k) {
      ls[wave][c0 + k] = s[k];
      lq[wave][c0 + k] = q[k];
    }
  }
  __syncthreads();
  if (tid < 64) {
    float ss = ls[0][tid] + ls[1][tid] + ls[2][tid] + ls[3][tid];
    float qq = lq[0][tid] + lq[1][tid] + lq[2][tid] + lq[3][tid];
    partials[blockIdx.x * 128 + tid] = ss;
    partials[blockIdx.x * 128 + 64 + tid] = qq;
  }
}

// ---------- finalize: self-reduce partials, normalize bf16 y -> fp32 out ----------
__global__ __launch_bounds__(256) void k_finalize(const ushort* __restrict__ y,
                                                  const float* __restrict__ partials,
                                                  const float* __restrict__ gamma,
                                                  const float* __restrict__ beta,
                                                  float* __restrict__ out,
                                                  float invN, int total8, int pb) {
  __shared__ float tmp[256];
  __shared__ float red[128];
  int tid = threadIdx.x;
  {
    int c = tid & 127;
    int half = tid >> 7;
    int hb = pb >> 1;
    float s = 0.f;
    for (int b = half * hb; b < (half + 1) * hb; ++b) s += partials[b * 128 + c];
    tmp[tid] = s;
    __syncthreads();
    if (tid < 128) red[tid] = tmp[tid] + tmp[tid + 128];
    __syncthreads();
  }
  int c0 = (tid & 7) << 3;
  float sc[8], sh[8];
#pragma unroll
  for (int k = 0; k < 8; ++k) {
    int c = c0 + k;
    float mean = red[c] * invN;
    float var = red[64 + c] * invN - mean * mean;
    float istd = rsqrtf(var + BN_EPS);
    float gm = gamma[c] * istd;
    sc[k] = gm;
    sh[k] = beta[c] - mean * gm;
  }
  int start = blockIdx.x * 256 + tid;
  int stride = gridDim.x * 256;  // %8==0
  for (int i = start; i < total8; i += stride) {
    uint4 v = *(const uint4*)&y[(size_t)i * 8];
    float f0 = bf2f((ushort)(v.x & 0xffff)), f1 = bf2f((ushort)(v.x >> 16));
    float f2 = bf2f((ushort)(v.y & 0xffff)), f3 = bf2f((ushort)(v.y >> 16));
    float f4 = bf2f((ushort)(v.z & 0xffff)), f5 = bf2f((ushort)(v.z >> 16));
    float f6 = bf2f((ushort)(v.w & 0xffff)), f7 = bf2f((ushort)(v.w >> 16));
    float4 o0 = make_float4(f0 * sc[0] + sh[0], f1 * sc[1] + sh[1],
                            f2 * sc[2] + sh[2], f3 * sc[3] + sh[3]);
    float4 o1 = make_float4(f4 * sc[4] + sh[4], f5 * sc[5] + sh[5],
                            f6 * sc[6] + sh[6], f7 * sc[7] + sh[7]);
    *(float4*)&out[(size_t)i * 8] = o0;
    *(float4*)&out[(size_t)i * 8 + 4] = o1;
  }
}

extern "C" void kernel_launch(void* const* d_in, const int* in_sizes, int n_in,
                              void* d_out, int out_size, void* d_ws, size_t ws_size,
                              hipStream_t stream) {
  const float* x = (const float*)d_in[0];
  const int* ei = (const int*)d_in[1];
  const float* W = (const float*)d_in[3];
  const float* bias = (const float*)d_in[4];
  const float* gamma = (const float*)d_in[5];
  const float* beta = (const float*)d_in[6];
  const int N = in_sizes[0] / IND;
  const int E = in_sizes[1] / 2;
  const int* rowp = ei;      // sources
  const int* colp = ei + E;  // targets
  float* out = (float*)d_out;

  char* wsb = (char*)d_ws;
  size_t off = 0;
  float* dis = (float*)(wsb + off);      off = align256(off + (size_t)N * 4);
  int* cnt = (int*)(wsb + off);          off = align256(off + (size_t)N * 4);
  int* offsets = (int*)(wsb + off);      off = align256(off + (size_t)N * 4);
  int* rank = (int*)(wsb + off);         off = align256(off + (size_t)E * 4);
  int* bsum = (int*)(wsb + off);         off = align256(off + 1024);
  int* gbexc = (int*)(wsb + off);        off = align256(off + 257 * 4);
  float* partials = (float*)(wsb + off); off = align256(off + 256 * 128 * 4);
  ushort* g = (ushort*)(wsb + off);      off = align256(off + (size_t)(N + 1) * HID * 2);
  ushort* ybf = (ushort*)(wsb + off);    off = align256(off + (size_t)N * HID * 2);
  int pcap = E + 8 * N;                  // padded capacity (sum <= E + 7N)
  int* pack = (int*)(wsb + off);         off = align256(off + (size_t)pcap * 4);

  const int NB = (N + 255) / 256;   // 196
  const int MMB = (N + 63) / 64;    // 782 matmul blocks
  const int PB = 782;               // place blocks

  int n4 = (N + 3) / 4;
  int p4 = pcap / 4;
  k_init<<<(p4 + 255) / 256, 256, 0, stream>>>((int4*)cnt, n4, (int4*)pack, p4,
                                               (uint4*)(g + (size_t)N * HID), N);
  k_deg_count<<<(E / 4 + 255) / 256, 256, 0, stream>>>(colp, cnt, rank, E / 4);
  k_scanA<<<NB, 256, 0, stream>>>(cnt, bsum, offsets, dis, N);
  k_fused<<<MMB + PB, 256, 0, stream>>>(x, W, dis, g, rowp, colp, rank, offsets,
                                        bsum, gbexc, pack, N, E, MMB, PB, NB);
  k_gather<<<(N + 3) / 4, 256, 0, stream>>>(offsets, gbexc, pack, dis, g, bias,
                                            ybf, N);
  int total8 = N * (HID / 8);
  k_stats<<<256, 256, 0, stream>>>(ybf, partials, total8);
  k_finalize<<<256, 256, 0, stream>>>(ybf, partials, gamma, beta, out,
                                      1.0f / (float)N, total8, 256);
}